// Round 16
// baseline (184.236 us; speedup 1.0000x reference)
//
#include <hip/hip_runtime.h>
#include <cstdint>

// ---------- types ----------
using bx8 = __attribute__((ext_vector_type(8))) __bf16;   // MFMA A/B fragment (8 bf16)
using us8 = __attribute__((ext_vector_type(8))) unsigned short;
using us4 = __attribute__((ext_vector_type(4))) unsigned short;
using fl8 = __attribute__((ext_vector_type(8))) float;
using fx4 = __attribute__((ext_vector_type(4))) float;    // MFMA C/D fragment

static __device__ inline unsigned short f2bf(float f) {
  unsigned u = __builtin_bit_cast(unsigned, f);
  unsigned r = 0x7FFFu + ((u >> 16) & 1u);   // round-to-nearest-even
  return (unsigned short)((u + r) >> 16);
}
static __device__ inline float bf2f(unsigned short s) {
  return __builtin_bit_cast(float, (unsigned)s << 16);
}

static __device__ inline fx4 mfma16(bx8 a, bx8 b, fx4 c) {
  return __builtin_amdgcn_mfma_f32_16x16x32_bf16(a, b, c, 0, 0, 0);
}

// async global->LDS, 16B/lane; dest = wave-uniform base + lane*16 (R9-proven w/ drain)
static __device__ inline void gload16(const void* g, void* lds) {
  __builtin_amdgcn_global_load_lds(
      (const __attribute__((address_space(1))) void*)g,
      (__attribute__((address_space(3))) void*)lds,
      16, 0, 0);
}
#define VMCNT(n) asm volatile("s_waitcnt vmcnt(" #n ")" ::: "memory")
// raw barrier (does NOT drain vmcnt, unlike __syncthreads) + compiler fences
static __device__ inline void wave_barrier() {
  __builtin_amdgcn_sched_barrier(0);
  __builtin_amdgcn_s_barrier();
  __builtin_amdgcn_sched_barrier(0);
}
// LDS-only barrier: drains lgkmcnt but NOT vmcnt.
static __device__ inline void lds_barrier() {
  __builtin_amdgcn_sched_barrier(0);
  asm volatile("s_waitcnt lgkmcnt(0)" ::: "memory");
  __builtin_amdgcn_s_barrier();
  __builtin_amdgcn_sched_barrier(0);
}

// DPP row_ror:k (VALU-latency cross-lane)
#define DPP_ROR(x, k) __builtin_bit_cast(float, __builtin_amdgcn_update_dpp( \
    __builtin_bit_cast(int, x), __builtin_bit_cast(int, x), 0x120 | (k), 0xF, 0xF, false))

static __device__ inline float rowmax16(float v) {
  v = fmaxf(v, DPP_ROR(v, 1));
  v = fmaxf(v, DPP_ROR(v, 2));
  v = fmaxf(v, DPP_ROR(v, 4));
  v = fmaxf(v, DPP_ROR(v, 8));
  return v;
}
static __device__ inline float rowsum16(float v) {
  v += DPP_ROR(v, 1);
  v += DPP_ROR(v, 2);
  v += DPP_ROR(v, 4);
  v += DPP_ROR(v, 8);
  return v;
}

// ---------- fp32 -> bf16 convert (R4-proven) ----------
__global__ __launch_bounds__(256) void f2b_kernel(const float* __restrict__ in,
                                                  unsigned short* __restrict__ out,
                                                  int n) {
  int i = (blockIdx.x * 256 + threadIdx.x) * 4;
  if (i >= n) return;
  float4 v = *reinterpret_cast<const float4*>(in + i);
  ushort4 o;
  o.x = f2bf(v.x); o.y = f2bf(v.y); o.z = f2bf(v.z); o.w = f2bf(v.w);
  *reinterpret_cast<ushort4*>(out + i) = o;
}

// ================= GEMM1: 128x256 tile, BK=32, depth-2 counted-vmcnt pipeline =================
// R16: BM 256->128 vs the R10-proven gemm256 — halves the straggler quantum:
// grid (24,16)=384 blocks, 3-buf LDS 72KB -> 2 blocks/CU -> ALL co-resident.
// Per-wave stage = 3 gloads (1 A + 2 B) -> steady-state VMCNT(3).
// Swizzle (write: slot s holds col s^(row&3); read: granule lg^(l16&3)) is
// row-length(64B)- and 16-row-alignment-preserving — identical to gemm256.
__global__ __launch_bounds__(512) void gemm128(const unsigned short* __restrict__ A,
                                               const unsigned short* __restrict__ B,
                                               unsigned short* __restrict__ C,
                                               int M, int N, int K) {
  __shared__ unsigned short ldsA[3][128 * 32];   // 3 x 8 KiB
  __shared__ unsigned short ldsB[3][256 * 32];   // 3 x 16 KiB

  const int tid = threadIdx.x;
  const int w = tid >> 6, l = tid & 63;
  const int l16 = l & 15, lg = l >> 4;
  const int wr = w >> 2, wc = w & 3;             // 2 M-waves x 4 N-waves
  const long mb = (long)blockIdx.y * 128, nb = (long)blockIdx.x * 256;

  const int lr = l >> 2;                          // row 0..15 within a gload
  const int sw = (((l & 3) ^ (lr & 3)) * 8);      // pre-swizzled col (elements)
  const unsigned short* Ag = A + (mb + w * 16 + lr) * (long)K + sw;   // 16 rows/wave
  const unsigned short* Bg = B + (nb + w * 32 + lr) * (long)K + sw;   // 32 rows/wave

  const int rdcol = ((lg ^ (l16 & 3)) * 16);

  const fx4 fz = {0.f, 0.f, 0.f, 0.f};
  fx4 acc[4][4];
#pragma unroll
  for (int i = 0; i < 4; ++i)
#pragma unroll
    for (int j = 0; j < 4; ++j) acc[i][j] = fz;

  const int nt = K >> 5;   // K/32 tiles

  auto stage = [&](int tp) {
    const int db = tp % 3;
    const unsigned short* as = Ag + tp * 32;
    const unsigned short* bs = Bg + tp * 32;
    char* al = (char*)&ldsA[db][0] + w * 1024;    // 16 rows x 64B per wave
    char* bl = (char*)&ldsB[db][0] + w * 2048;    // 32 rows x 64B per wave
    gload16(as, al);
    gload16(bs, bl);
    gload16(bs + 16 * (long)K, bl + 1024);
  };

  auto compute = [&](int bt) {
    const char* Ab = (const char*)&ldsA[bt][0] + (wr * 64 + l16) * 64 + rdcol;
    const char* Bb = (const char*)&ldsB[bt][0] + (wc * 64 + l16) * 64 + rdcol;
    bx8 bf[4];
#pragma unroll
    for (int nf = 0; nf < 4; ++nf)
      bf[nf] = *reinterpret_cast<const bx8*>(Bb + nf * 1024);
    __builtin_amdgcn_s_setprio(1);
#pragma unroll
    for (int mf = 0; mf < 4; ++mf) {
      bx8 av = *reinterpret_cast<const bx8*>(Ab + mf * 1024);
#pragma unroll
      for (int nf = 0; nf < 4; ++nf)
        acc[mf][nf] = mfma16(av, bf[nf], acc[mf][nf]);
    }
    __builtin_amdgcn_s_setprio(0);
  };

  // prologue: 2 tiles in flight; wait tile0 (6 outstanding -> 3)
  stage(0); stage(1);
  VMCNT(3);
  wave_barrier();

  int t = 0;
  for (; t < nt - 2; ++t) {
    stage(t + 2);        // 3 issues -> 6 outstanding
    compute(t % 3);
    VMCNT(3);            // retire tile t+1's 3 loads
    wave_barrier();
  }
  compute(t % 3); VMCNT(0); wave_barrier(); ++t;   // t = nt-2
  compute(t % 3);                                  // t = nt-1

  // epilogue: C/D layout col = lane&15, row = (lane>>4)*4 + reg  [m89-verified]
#pragma unroll
  for (int mf = 0; mf < 4; ++mf)
#pragma unroll
    for (int nf = 0; nf < 4; ++nf)
#pragma unroll
      for (int r = 0; r < 4; ++r) {
        const long row = mb + wr * 64 + mf * 16 + lg * 4 + r;
        const long col = nb + wc * 64 + nf * 16 + l16;
        C[row * N + col] = f2bf(acc[mf][nf][r]);
      }
}

// ---------- staging-reg type per operand dtype (R8-proven fold GEMM) ----------
template <typename T> struct RegOf { using type = us8; };
template <> struct RegOf<float>  { using type = fl8; };

template <typename T>
static __device__ inline typename RegOf<T>::type load8(const T* p) {
  return *reinterpret_cast<const typename RegOf<T>::type*>(p);
}
static __device__ inline us8 toBf(us8 v) { return v; }
static __device__ inline us8 toBf(fl8 f) {
  us8 o;
#pragma unroll
  for (int j = 0; j < 8; ++j) {
    __bf16 b = (__bf16)f[j];
    o[j] = __builtin_bit_cast(unsigned short, b);
  }
  return o;
}

// ---------- GEMM2: R8-proven 128x128 reg-staged fold kernel + vmcnt-free barriers ----------
template <typename TA, typename TB, bool F32OUT>
__global__ __launch_bounds__(256) void gemm_bt(const TA* __restrict__ A,
                                               const TB* __restrict__ B,
                                               void* __restrict__ Cp,
                                               int M, int N, int K) {
  __shared__ alignas(16) unsigned short As[128 * 64];
  __shared__ alignas(16) unsigned short Bs[128 * 64];
  const int tid = threadIdx.x;
  const int w = tid >> 6, l = tid & 63;
  const int l16 = l & 15, lg = l >> 4;
  const int wr = w >> 1, wc = w & 1;
  const long mb = (long)blockIdx.y * 128, nb = (long)blockIdx.x * 128;

  const fx4 fz = {0.f, 0.f, 0.f, 0.f};
  fx4 acc[4][4];
#pragma unroll
  for (int i = 0; i < 4; ++i)
#pragma unroll
    for (int j = 0; j < 4; ++j) acc[i][j] = fz;

  const int sr  = tid >> 3;
  const int sc8 = (tid & 7) * 8;
  const int wbc = sc8 * 2;

  typename RegOf<TA>::type rA[4];
  typename RegOf<TB>::type rB[4];

#pragma unroll
  for (int p = 0; p < 4; ++p) {
    const int row = p * 32 + sr;
    rA[p] = load8(A + (mb + row) * (long)K + sc8);
    rB[p] = load8(B + (nb + row) * (long)K + sc8);
  }

  for (int k0 = 0; k0 < K; k0 += 64) {
    lds_barrier();   // prior iter's LDS reads done (no vmcnt drain)
#pragma unroll
    for (int p = 0; p < 4; ++p) {
      const int row = p * 32 + sr;
      const int eo = row * 64 + ((wbc ^ ((row & 7) << 4)) >> 1);
      *reinterpret_cast<us8*>(&As[eo]) = toBf(rA[p]);
      *reinterpret_cast<us8*>(&Bs[eo]) = toBf(rB[p]);
    }
    if (k0 + 64 < K) {
#pragma unroll
      for (int p = 0; p < 4; ++p) {
        const int row = p * 32 + sr;
        rA[p] = load8(A + (mb + row) * (long)K + k0 + 64 + sc8);
        rB[p] = load8(B + (nb + row) * (long)K + k0 + 64 + sc8);
      }
    }
    lds_barrier();   // tiles resident; prefetch loads stay in flight
#pragma unroll
    for (int kk = 0; kk < 2; ++kk) {
      bx8 a[4], b[4];
#pragma unroll
      for (int mf = 0; mf < 4; ++mf) {
        const int ra = wr * 64 + mf * 16 + l16;
        const int bc = kk * 64 + lg * 16;
        a[mf] = *reinterpret_cast<const bx8*>(&As[ra * 64 + ((bc ^ ((ra & 7) << 4)) >> 1)]);
      }
#pragma unroll
      for (int nf = 0; nf < 4; ++nf) {
        const int rb_ = wc * 64 + nf * 16 + l16;
        const int bc = kk * 64 + lg * 16;
        b[nf] = *reinterpret_cast<const bx8*>(&Bs[rb_ * 64 + ((bc ^ ((rb_ & 7) << 4)) >> 1)]);
      }
#pragma unroll
      for (int mf = 0; mf < 4; ++mf)
#pragma unroll
        for (int nf = 0; nf < 4; ++nf)
          acc[mf][nf] = mfma16(a[mf], b[nf], acc[mf][nf]);
    }
  }

#pragma unroll
  for (int mf = 0; mf < 4; ++mf)
#pragma unroll
    for (int nf = 0; nf < 4; ++nf)
#pragma unroll
      for (int r = 0; r < 4; ++r) {
        const long row = mb + wr * 64 + mf * 16 + lg * 4 + r;
        const long col = nb + wc * 64 + nf * 16 + l16;
        if (F32OUT)
          ((float*)Cp)[row * N + col] = acc[mf][nf][r];
        else
          ((unsigned short*)Cp)[row * N + col] = f2bf(acc[mf][nf][r]);
      }
}

// ---------- flash attention (causal) — R13/R15-proven body, FROZEN ----------
//   smem: Ks [64 rows][256B] swz key row&15   @ 0      (16 KiB)
//         Vt [128 rows][128B] swz key row&7   @ 16384  (16 KiB)
//         Ps 4 x [16 rows][128B] swz key row&7 @ 32768 (8 KiB)
__global__ __launch_bounds__(256) void fa_kernel(const unsigned short* __restrict__ qkv,
                                                 unsigned short* __restrict__ Obuf,
                                                 float* __restrict__ ML) {
  __shared__ alignas(16) char smem[40960];

  const int id = blockIdx.x;
  const int h = id & 15, i = id >> 4;
  int qt, ck;
  if (i < 32)      { qt = 31 - (i >> 2); ck = i & 3; }
  else if (i < 56) { const int j = i - 32; qt = 23 - j / 3; ck = j % 3; }
  else if (i < 72) { const int j = i - 56; qt = 15 - (j >> 1); ck = j & 1; }
  else             { qt = 7 - (i - 72); ck = 0; }
  const int t0 = ck * 8;
  const int t1 = min(t0 + 8, qt + 1);
  const int qb = qt * 64;

  const int tid = threadIdx.x;
  const int w = tid >> 6, l = tid & 63;
  const int l16 = l & 15, lg = l >> 4;
  const fx4 fz = {0.f, 0.f, 0.f, 0.f};

  const int kr = tid >> 4, ksl = tid & 15;
  const int kg = tid & 15, db = tid >> 4;
  const int kc8 = ksl * 8;

  bx8 qf[4];
  {
    const long qrow = qb + w * 16 + l16;
    const unsigned short* qp = qkv + qrow * 6144L + h * 128 + lg * 8;
#pragma unroll
    for (int kc = 0; kc < 4; ++kc)
      qf[kc] = *reinterpret_cast<const bx8*>(qp + kc * 32);
  }

  fx4 o_acc[8];
#pragma unroll
  for (int i2 = 0; i2 < 8; ++i2) o_acc[i2] = fz;
  float m_r[4] = {-3e38f, -3e38f, -3e38f, -3e38f};
  float l_r[4] = {0.f, 0.f, 0.f, 0.f};

  us8 rK[4], rV[4];
  {
    const long kvb = (long)t0 * 64;
#pragma unroll
    for (int p = 0; p < 4; ++p)
      rK[p] = *reinterpret_cast<const us8*>(qkv + (kvb + p * 16 + kr) * 6144L + 2048 + h * 128 + kc8);
#pragma unroll
    for (int p = 0; p < 4; ++p)
      rV[p] = *reinterpret_cast<const us8*>(qkv + (kvb + kg * 4 + p) * 6144L + 4096 + h * 128 + db * 8);
  }

  const float sc2 = 0.1275173831f;  // (1/sqrt(128)) * log2(e)
  char* const psb = smem + 32768 + w * 2048;

  for (int t = t0; t < t1; ++t) {
    lds_barrier();

#pragma unroll
    for (int p = 0; p < 4; ++p)
      *reinterpret_cast<us8*>(smem + (p * 16 + kr) * 256 + ((ksl ^ kr) << 4)) = rK[p];
#pragma unroll
    for (int j = 0; j < 8; ++j) {
      us4 vw = {rV[0][j], rV[1][j], rV[2][j], rV[3][j]};
      *reinterpret_cast<us4*>(smem + 16384 + (db * 8 + j) * 128 +
                              (((kg >> 1) ^ j) << 4) + ((kg & 1) << 3)) = vw;
    }

    if (t + 1 < t1) {
      const long kvb = (long)(t + 1) * 64;
#pragma unroll
      for (int p = 0; p < 4; ++p)
        rK[p] = *reinterpret_cast<const us8*>(qkv + (kvb + p * 16 + kr) * 6144L + 2048 + h * 128 + kc8);
#pragma unroll
      for (int p = 0; p < 4; ++p)
        rV[p] = *reinterpret_cast<const us8*>(qkv + (kvb + kg * 4 + p) * 6144L + 4096 + h * 128 + db * 8);
    }
    lds_barrier();

    fx4 s[4];
#pragma unroll
    for (int nf = 0; nf < 4; ++nf) s[nf] = fz;
#pragma unroll
    for (int kc = 0; kc < 4; ++kc) {
#pragma unroll
      for (int nf = 0; nf < 4; ++nf) {
        const int rl = nf * 16 + l16;
        bx8 kb = *reinterpret_cast<const bx8*>(smem + rl * 256 + (((kc * 4 + lg) ^ l16) << 4));
        s[nf] = mfma16(qf[kc], kb, s[nf]);
      }
    }

    if (t == qt) {
#pragma unroll
      for (int nf = 0; nf < 4; ++nf) {
        const int kv_abs = t * 64 + nf * 16 + l16;
#pragma unroll
        for (int r = 0; r < 4; ++r) {
          const int q_abs = qb + w * 16 + lg * 4 + r;
          if (kv_abs > q_abs) s[nf][r] = -3e38f;
        }
      }
    }

    float rm_[4];
    bool st = true;
#pragma unroll
    for (int r = 0; r < 4; ++r) {
      float rm = fmaxf(fmaxf(s[0][r], s[1][r]), fmaxf(s[2][r], s[3][r]));
      rm_[r] = rowmax16(rm);
      st = st && (rm_[r] - m_r[r] <= 62.7f);
    }
    float pv[4][4];
    if (__all(st ? 1 : 0)) {
#pragma unroll
      for (int r = 0; r < 4; ++r) {
        float rs = 0.f;
#pragma unroll
        for (int nf = 0; nf < 4; ++nf) {
          const float p = exp2f((s[nf][r] - m_r[r]) * sc2);
          pv[nf][r] = p;
          rs += p;
        }
        l_r[r] += rowsum16(rs);
      }
    } else {
#pragma unroll
      for (int r = 0; r < 4; ++r) {
        const float mn = fmaxf(m_r[r], rm_[r]);
        const float fac = exp2f((m_r[r] - mn) * sc2);
        m_r[r] = mn;
        float rs = 0.f;
#pragma unroll
        for (int nf = 0; nf < 4; ++nf) {
          const float p = exp2f((s[nf][r] - mn) * sc2);
          pv[nf][r] = p;
          rs += p;
        }
        l_r[r] = l_r[r] * fac + rowsum16(rs);
#pragma unroll
        for (int nf = 0; nf < 8; ++nf) o_acc[nf][r] *= fac;
      }
    }

#pragma unroll
    for (int nf = 0; nf < 4; ++nf)
#pragma unroll
      for (int r = 0; r < 4; ++r) {
        const int ro = lg * 4 + r;
        *reinterpret_cast<unsigned short*>(
            psb + ro * 128 + (((nf * 2 + (l16 >> 3)) ^ (ro & 7)) << 4) + ((l16 & 7) << 1)) =
            __builtin_bit_cast(unsigned short, (__bf16)pv[nf][r]);
      }

    bx8 pa[2];
#pragma unroll
    for (int kc = 0; kc < 2; ++kc)
      pa[kc] = *reinterpret_cast<const bx8*>(psb + l16 * 128 + (((kc * 4 + lg) ^ (l16 & 7)) << 4));

#pragma unroll
    for (int nf = 0; nf < 8; ++nf) {
#pragma unroll
      for (int kc = 0; kc < 2; ++kc) {
        bx8 vb = *reinterpret_cast<const bx8*>(smem + 16384 + (nf * 16 + l16) * 128 +
                                               (((kc * 4 + lg) ^ (l16 & 7)) << 4));
        o_acc[nf] = mfma16(pa[kc], vb, o_acc[nf]);
      }
    }
  }

  unsigned short* ob = Obuf + (long)id * 8192;
#pragma unroll
  for (int nf = 0; nf < 8; ++nf)
#pragma unroll
    for (int r = 0; r < 4; ++r) {
      const int row = w * 16 + lg * 4 + r;
      ob[row * 128 + nf * 16 + l16] = f2bf(o_acc[nf][r]);
    }
  if (l16 == 0) {
#pragma unroll
    for (int r = 0; r < 4; ++r) {
      const int row = w * 16 + lg * 4 + r;
      ML[((long)id * 64 + row) * 2 + 0] = m_r[r];
      ML[((long)id * 64 + row) * 2 + 1] = l_r[r];
    }
  }
}

// ---------- combine <=4 chunk partials into attnb (R11-proven) ----------
__global__ __launch_bounds__(256) void fa_combine(const unsigned short* __restrict__ Obuf,
                                                  const float* __restrict__ ML,
                                                  unsigned short* __restrict__ out) {
  const int p = blockIdx.x;
  const int qt = p >> 4, h = p & 15;
  const int nc = (qt + 8) >> 3;
  const int tid = threadIdx.x;
  const int row = tid >> 2;
  const int c0 = (tid & 3) * 32;
  const float sc2 = 0.1275173831f;

  int ids[4];
#pragma unroll
  for (int k = 0; k < 4; ++k) {
    int ib;
    if (qt >= 24)      ib = (31 - qt) * 4 + k;
    else if (qt >= 16) ib = 32 + (23 - qt) * 3 + k;
    else if (qt >= 8)  ib = 56 + (15 - qt) * 2 + k;
    else               ib = 72 + (7 - qt);
    ids[k] = ib * 16 + h;
  }

  float mk[4], lk[4];
  float m = -3e38f;
#pragma unroll
  for (int k = 0; k < 4; ++k)
    if (k < nc) {
      mk[k] = ML[((long)ids[k] * 64 + row) * 2 + 0];
      lk[k] = ML[((long)ids[k] * 64 + row) * 2 + 1];
      m = fmaxf(m, mk[k]);
    }
  float fk[4], denom = 0.f;
#pragma unroll
  for (int k = 0; k < 4; ++k)
    if (k < nc) {
      fk[k] = exp2f((mk[k] - m) * sc2);
      denom += lk[k] * fk[k];
    }
  const float inv = 1.0f / denom;

  float acc[32];
#pragma unroll
  for (int j = 0; j < 32; ++j) acc[j] = 0.f;
#pragma unroll
  for (int k = 0; k < 4; ++k)
    if (k < nc) {
      const unsigned short* ob = Obuf + (long)ids[k] * 8192 + row * 128 + c0;
      const float f = fk[k];
#pragma unroll
      for (int jj = 0; jj < 4; ++jj) {
        us8 a = *reinterpret_cast<const us8*>(ob + jj * 8);
#pragma unroll
        for (int j2 = 0; j2 < 8; ++j2) acc[jj * 8 + j2] += bf2f(a[j2]) * f;
      }
    }

  unsigned short* dst = out + (long)(qt * 64 + row) * 2048 + h * 128 + c0;
#pragma unroll
  for (int jj = 0; jj < 4; ++jj) {
    ushort4 o0, o1;
    o0.x = f2bf(acc[jj * 8 + 0] * inv);
    o0.y = f2bf(acc[jj * 8 + 1] * inv);
    o0.z = f2bf(acc[jj * 8 + 2] * inv);
    o0.w = f2bf(acc[jj * 8 + 3] * inv);
    o1.x = f2bf(acc[jj * 8 + 4] * inv);
    o1.y = f2bf(acc[jj * 8 + 5] * inv);
    o1.z = f2bf(acc[jj * 8 + 6] * inv);
    o1.w = f2bf(acc[jj * 8 + 7] * inv);
    *reinterpret_cast<ushort4*>(dst + jj * 8) = o0;
    *reinterpret_cast<ushort4*>(dst + jj * 8 + 4) = o1;
  }
}

// ---------- launch ----------
// Interface (confirmed R4): inputs fp32, output fp32.
// Workspace plan (peak 56 MiB):
//   wab   [0, 24 MiB)     bf16 W_attn (dead after GEMM1)
//   qkvb  [24, 48 MiB)    bf16 qkv
//   xb    [48, 56 MiB)    bf16 x (dead after GEMM1)
//   -- after GEMM1, overlaying dead regions:
//   Obuf  [0, 20 MiB)     1280 x 64x128 bf16 partial O numerators
//   ML    [20, 20.625)    1280 x 64 x (m,l) fp32
//   attnb [48, 56 MiB)    bf16 attn out (overlays dead xb)
extern "C" void kernel_launch(void* const* d_in, const int* in_sizes, int n_in,
                              void* d_out, int out_size, void* d_ws, size_t ws_size,
                              hipStream_t stream) {
  const float* x  = (const float*)d_in[0];   // (2048, 2048) fp32
  const float* Wa = (const float*)d_in[1];   // (6144, 2048) fp32
  const float* Wp = (const float*)d_in[2];   // (2048, 2048) fp32
  float* out = (float*)d_out;                // (2048, 2048) fp32
  char* ws = (char*)d_ws;

  unsigned short* wab   = (unsigned short*)(ws);                 // 24 MiB
  unsigned short* qkvb  = (unsigned short*)(ws + (24ull << 20)); // 24 MiB
  unsigned short* xb    = (unsigned short*)(ws + (48ull << 20)); //  8 MiB
  unsigned short* Obuf  = (unsigned short*)(ws);                 // 20 MiB (after GEMM1)
  float*          ML    = (float*)(ws + (20ull << 20));          // 640 KiB (after GEMM1)
  unsigned short* attnb = (unsigned short*)(ws + (48ull << 20)); //  8 MiB (after GEMM1)

  f2b_kernel<<<4096, 256, 0, stream>>>(x, xb, 2048 * 2048);
  f2b_kernel<<<12288, 256, 0, stream>>>(Wa, wab, 6144 * 2048);

  // qkv = x @ W_attn^T : M=2048, N=6144, K=2048 — 128x256 tiles, 384 blocks (uniform fill)
  gemm128<<<dim3(24, 16), 512, 0, stream>>>(xb, wab, qkvb, 2048, 6144, 2048);

  // causal flash attention: 1280 uniform 8-tile chunk items (heavy first)
  fa_kernel<<<1280, 256, 0, stream>>>(qkvb, Obuf, ML);

  // merge 1..4 chunk partials per (qt, h)
  fa_combine<<<512, 256, 0, stream>>>(Obuf, ML, attnb);

  // out = attn @ W_proj^T : M=2048, N=2048, K=2048 (A bf16, B fp32 fold, fp32 out)
  gemm_bt<unsigned short, float, true><<<dim3(16, 16), 256, 0, stream>>>(attnb, Wp, (void*)out, 2048, 2048, 2048);
}

// Round 17
// 183.776 us; speedup vs baseline: 1.0025x; 1.0025x over previous
//
#include <hip/hip_runtime.h>
#include <cstdint>

// ---------- types ----------
using bx8 = __attribute__((ext_vector_type(8))) __bf16;   // MFMA A/B fragment (8 bf16)
using us8 = __attribute__((ext_vector_type(8))) unsigned short;
using us4 = __attribute__((ext_vector_type(4))) unsigned short;
using fl8 = __attribute__((ext_vector_type(8))) float;
using fx4 = __attribute__((ext_vector_type(4))) float;    // MFMA C/D fragment

static __device__ inline unsigned short f2bf(float f) {
  unsigned u = __builtin_bit_cast(unsigned, f);
  unsigned r = 0x7FFFu + ((u >> 16) & 1u);   // round-to-nearest-even
  return (unsigned short)((u + r) >> 16);
}
static __device__ inline float bf2f(unsigned short s) {
  return __builtin_bit_cast(float, (unsigned)s << 16);
}

static __device__ inline fx4 mfma16(bx8 a, bx8 b, fx4 c) {
  return __builtin_amdgcn_mfma_f32_16x16x32_bf16(a, b, c, 0, 0, 0);
}

// async global->LDS, 16B/lane; dest = wave-uniform base + lane*16 (R9-proven w/ drain)
static __device__ inline void gload16(const void* g, void* lds) {
  __builtin_amdgcn_global_load_lds(
      (const __attribute__((address_space(1))) void*)g,
      (__attribute__((address_space(3))) void*)lds,
      16, 0, 0);
}
#define VMCNT(n) asm volatile("s_waitcnt vmcnt(" #n ")" ::: "memory")
// raw barrier (does NOT drain vmcnt, unlike __syncthreads) + compiler fences
static __device__ inline void wave_barrier() {
  __builtin_amdgcn_sched_barrier(0);
  __builtin_amdgcn_s_barrier();
  __builtin_amdgcn_sched_barrier(0);
}
// LDS-only barrier: drains lgkmcnt but NOT vmcnt.
static __device__ inline void lds_barrier() {
  __builtin_amdgcn_sched_barrier(0);
  asm volatile("s_waitcnt lgkmcnt(0)" ::: "memory");
  __builtin_amdgcn_s_barrier();
  __builtin_amdgcn_sched_barrier(0);
}

// DPP row_ror:k (VALU-latency cross-lane)
#define DPP_ROR(x, k) __builtin_bit_cast(float, __builtin_amdgcn_update_dpp( \
    __builtin_bit_cast(int, x), __builtin_bit_cast(int, x), 0x120 | (k), 0xF, 0xF, false))

static __device__ inline float rowmax16(float v) {
  v = fmaxf(v, DPP_ROR(v, 1));
  v = fmaxf(v, DPP_ROR(v, 2));
  v = fmaxf(v, DPP_ROR(v, 4));
  v = fmaxf(v, DPP_ROR(v, 8));
  return v;
}
static __device__ inline float rowsum16(float v) {
  v += DPP_ROR(v, 1);
  v += DPP_ROR(v, 2);
  v += DPP_ROR(v, 4);
  v += DPP_ROR(v, 8);
  return v;
}

// ---------- fp32 -> bf16 convert (R4-proven) ----------
__global__ __launch_bounds__(256) void f2b_kernel(const float* __restrict__ in,
                                                  unsigned short* __restrict__ out,
                                                  int n) {
  int i = (blockIdx.x * 256 + threadIdx.x) * 4;
  if (i >= n) return;
  float4 v = *reinterpret_cast<const float4*>(in + i);
  ushort4 o;
  o.x = f2bf(v.x); o.y = f2bf(v.y); o.z = f2bf(v.z); o.w = f2bf(v.w);
  *reinterpret_cast<ushort4*>(out + i) = o;
}

// ================= GEMM1: 256x256 tile, BK=32, depth-3 counted-vmcnt pipeline (R10/R15-proven) =================
__global__ __launch_bounds__(512, 2) void gemm256(const unsigned short* __restrict__ A,
                                                  const unsigned short* __restrict__ B,
                                                  unsigned short* __restrict__ C,
                                                  int M, int N, int K) {
  __shared__ unsigned short lds[4][2][256 * 32];   // [buf][A/B][row*32 + col]

  const int tid = threadIdx.x;
  const int w = tid >> 6, l = tid & 63;
  const int l16 = l & 15, lg = l >> 4;
  const int wr = w >> 2, wc = w & 3;
  const long mb = (long)blockIdx.y * 256, nb = (long)blockIdx.x * 256;

  const int lr = l >> 2;
  const int sw = (((l & 3) ^ (lr & 3)) * 8);       // pre-swizzled col (elements)
  const unsigned short* Ag = A + (mb + w * 32 + lr) * (long)K + sw;
  const unsigned short* Bg = B + (nb + w * 32 + lr) * (long)K + sw;

  const int rdcol = ((lg ^ (l16 & 3)) * 16);

  const fx4 fz = {0.f, 0.f, 0.f, 0.f};
  fx4 acc[8][4];
#pragma unroll
  for (int i = 0; i < 8; ++i)
#pragma unroll
    for (int j = 0; j < 4; ++j) acc[i][j] = fz;

  const int nt = K >> 5;   // K/32 tiles

  auto stage = [&](int tp) {
    const int db = tp & 3;
    const unsigned short* as = Ag + tp * 32;
    const unsigned short* bs = Bg + tp * 32;
    char* al = (char*)&lds[db][0][0] + w * 32 * 64;
    char* bl = (char*)&lds[db][1][0] + w * 32 * 64;
    gload16(as, al);
    gload16(as + 16 * (long)K, al + 1024);
    gload16(bs, bl);
    gload16(bs + 16 * (long)K, bl + 1024);
  };

  auto compute = [&](int bt) {
    const char* Ab = (const char*)&lds[bt][0][0] + (wr * 128 + l16) * 64 + rdcol;
    const char* Bb = (const char*)&lds[bt][1][0] + (wc * 64 + l16) * 64 + rdcol;
    bx8 bf[4];
#pragma unroll
    for (int nf = 0; nf < 4; ++nf)
      bf[nf] = *reinterpret_cast<const bx8*>(Bb + nf * 1024);
    __builtin_amdgcn_s_setprio(1);
#pragma unroll
    for (int mf = 0; mf < 8; ++mf) {
      bx8 av = *reinterpret_cast<const bx8*>(Ab + mf * 1024);
#pragma unroll
      for (int nf = 0; nf < 4; ++nf)
        acc[mf][nf] = mfma16(av, bf[nf], acc[mf][nf]);
    }
    __builtin_amdgcn_s_setprio(0);
  };

  stage(0); stage(1); stage(2);
  VMCNT(8);
  wave_barrier();

  int t = 0;
  for (; t < nt - 3; ++t) {
    stage(t + 3);
    compute(t & 3);
    VMCNT(8);
    wave_barrier();
  }
  compute(t & 3); VMCNT(4); wave_barrier(); ++t;
  compute(t & 3); VMCNT(0); wave_barrier(); ++t;
  compute(t & 3);

#pragma unroll
  for (int mf = 0; mf < 8; ++mf)
#pragma unroll
    for (int nf = 0; nf < 4; ++nf)
#pragma unroll
      for (int r = 0; r < 4; ++r) {
        const long row = mb + wr * 128 + mf * 16 + lg * 4 + r;
        const long col = nb + wc * 64 + nf * 16 + l16;
        C[row * N + col] = f2bf(acc[mf][nf][r]);
      }
}

// ================= GEMM2: 128x128 tile, BK=32, SAME depth-3 counted-vmcnt ledger =================
// R17: gemm256's pipeline (4 gloads/wave/stage, 4-buf, VMCNT(8) steady) at 128x128
// geometry: 4 waves (2x2), per-wave 64x64 (acc[4][4], 16 MFMA/step). Grid 16x16 =
// 256 blocks = exactly 1/CU (uniform fill). A,B bf16 (Wp pre-converted); fp32 out.
__global__ __launch_bounds__(256) void gemm2p(const unsigned short* __restrict__ A,
                                              const unsigned short* __restrict__ B,
                                              float* __restrict__ C,
                                              int M, int N, int K) {
  __shared__ unsigned short lds[4][2][128 * 32];   // 4 bufs x (A 8KB + B 8KB) = 64 KiB

  const int tid = threadIdx.x;
  const int w = tid >> 6, l = tid & 63;            // 4 waves
  const int l16 = l & 15, lg = l >> 4;
  const int wr = w >> 1, wc = w & 1;
  const long mb = (long)blockIdx.y * 128, nb = (long)blockIdx.x * 128;

  const int lr = l >> 2;
  const int sw = (((l & 3) ^ (lr & 3)) * 8);       // pre-swizzled col (elements)
  const unsigned short* Ag = A + (mb + w * 32 + lr) * (long)K + sw;
  const unsigned short* Bg = B + (nb + w * 32 + lr) * (long)K + sw;

  const int rdcol = ((lg ^ (l16 & 3)) * 16);

  const fx4 fz = {0.f, 0.f, 0.f, 0.f};
  fx4 acc[4][4];
#pragma unroll
  for (int i = 0; i < 4; ++i)
#pragma unroll
    for (int j = 0; j < 4; ++j) acc[i][j] = fz;

  const int nt = K >> 5;   // K/32 tiles

  auto stage = [&](int tp) {
    const int db = tp & 3;
    const unsigned short* as = Ag + tp * 32;
    const unsigned short* bs = Bg + tp * 32;
    char* al = (char*)&lds[db][0][0] + w * 32 * 64;   // 32 rows x 64B per wave
    char* bl = (char*)&lds[db][1][0] + w * 32 * 64;
    gload16(as, al);
    gload16(as + 16 * (long)K, al + 1024);
    gload16(bs, bl);
    gload16(bs + 16 * (long)K, bl + 1024);
  };

  auto compute = [&](int bt) {
    const char* Ab = (const char*)&lds[bt][0][0] + (wr * 64 + l16) * 64 + rdcol;
    const char* Bb = (const char*)&lds[bt][1][0] + (wc * 64 + l16) * 64 + rdcol;
    bx8 bf[4];
#pragma unroll
    for (int nf = 0; nf < 4; ++nf)
      bf[nf] = *reinterpret_cast<const bx8*>(Bb + nf * 1024);
    __builtin_amdgcn_s_setprio(1);
#pragma unroll
    for (int mf = 0; mf < 4; ++mf) {
      bx8 av = *reinterpret_cast<const bx8*>(Ab + mf * 1024);
#pragma unroll
      for (int nf = 0; nf < 4; ++nf)
        acc[mf][nf] = mfma16(av, bf[nf], acc[mf][nf]);
    }
    __builtin_amdgcn_s_setprio(0);
  };

  stage(0); stage(1); stage(2);
  VMCNT(8);
  wave_barrier();

  int t = 0;
  for (; t < nt - 3; ++t) {
    stage(t + 3);        // 4 issues -> 12 outstanding
    compute(t & 3);
    VMCNT(8);            // retire tile t+1's 4 loads
    wave_barrier();
  }
  compute(t & 3); VMCNT(4); wave_barrier(); ++t;
  compute(t & 3); VMCNT(0); wave_barrier(); ++t;
  compute(t & 3);

  // epilogue: C/D layout col = lane&15, row = (lane>>4)*4 + reg  [m89-verified]
#pragma unroll
  for (int mf = 0; mf < 4; ++mf)
#pragma unroll
    for (int nf = 0; nf < 4; ++nf)
#pragma unroll
      for (int r = 0; r < 4; ++r) {
        const long row = mb + wr * 64 + mf * 16 + lg * 4 + r;
        const long col = nb + wc * 64 + nf * 16 + l16;
        C[row * N + col] = acc[mf][nf][r];
      }
}

// ---------- flash attention (causal) — R13/R15-proven body, FROZEN ----------
//   smem: Ks [64 rows][256B] swz key row&15   @ 0      (16 KiB)
//         Vt [128 rows][128B] swz key row&7   @ 16384  (16 KiB)
//         Ps 4 x [16 rows][128B] swz key row&7 @ 32768 (8 KiB)
__global__ __launch_bounds__(256) void fa_kernel(const unsigned short* __restrict__ qkv,
                                                 unsigned short* __restrict__ Obuf,
                                                 float* __restrict__ ML) {
  __shared__ alignas(16) char smem[40960];

  const int id = blockIdx.x;
  const int h = id & 15, i = id >> 4;
  int qt, ck;
  if (i < 32)      { qt = 31 - (i >> 2); ck = i & 3; }
  else if (i < 56) { const int j = i - 32; qt = 23 - j / 3; ck = j % 3; }
  else if (i < 72) { const int j = i - 56; qt = 15 - (j >> 1); ck = j & 1; }
  else             { qt = 7 - (i - 72); ck = 0; }
  const int t0 = ck * 8;
  const int t1 = min(t0 + 8, qt + 1);
  const int qb = qt * 64;

  const int tid = threadIdx.x;
  const int w = tid >> 6, l = tid & 63;
  const int l16 = l & 15, lg = l >> 4;
  const fx4 fz = {0.f, 0.f, 0.f, 0.f};

  const int kr = tid >> 4, ksl = tid & 15;
  const int kg = tid & 15, db = tid >> 4;
  const int kc8 = ksl * 8;

  bx8 qf[4];
  {
    const long qrow = qb + w * 16 + l16;
    const unsigned short* qp = qkv + qrow * 6144L + h * 128 + lg * 8;
#pragma unroll
    for (int kc = 0; kc < 4; ++kc)
      qf[kc] = *reinterpret_cast<const bx8*>(qp + kc * 32);
  }

  fx4 o_acc[8];
#pragma unroll
  for (int i2 = 0; i2 < 8; ++i2) o_acc[i2] = fz;
  float m_r[4] = {-3e38f, -3e38f, -3e38f, -3e38f};
  float l_r[4] = {0.f, 0.f, 0.f, 0.f};

  us8 rK[4], rV[4];
  {
    const long kvb = (long)t0 * 64;
#pragma unroll
    for (int p = 0; p < 4; ++p)
      rK[p] = *reinterpret_cast<const us8*>(qkv + (kvb + p * 16 + kr) * 6144L + 2048 + h * 128 + kc8);
#pragma unroll
    for (int p = 0; p < 4; ++p)
      rV[p] = *reinterpret_cast<const us8*>(qkv + (kvb + kg * 4 + p) * 6144L + 4096 + h * 128 + db * 8);
  }

  const float sc2 = 0.1275173831f;  // (1/sqrt(128)) * log2(e)
  char* const psb = smem + 32768 + w * 2048;

  for (int t = t0; t < t1; ++t) {
    lds_barrier();

#pragma unroll
    for (int p = 0; p < 4; ++p)
      *reinterpret_cast<us8*>(smem + (p * 16 + kr) * 256 + ((ksl ^ kr) << 4)) = rK[p];
#pragma unroll
    for (int j = 0; j < 8; ++j) {
      us4 vw = {rV[0][j], rV[1][j], rV[2][j], rV[3][j]};
      *reinterpret_cast<us4*>(smem + 16384 + (db * 8 + j) * 128 +
                              (((kg >> 1) ^ j) << 4) + ((kg & 1) << 3)) = vw;
    }

    if (t + 1 < t1) {
      const long kvb = (long)(t + 1) * 64;
#pragma unroll
      for (int p = 0; p < 4; ++p)
        rK[p] = *reinterpret_cast<const us8*>(qkv + (kvb + p * 16 + kr) * 6144L + 2048 + h * 128 + kc8);
#pragma unroll
      for (int p = 0; p < 4; ++p)
        rV[p] = *reinterpret_cast<const us8*>(qkv + (kvb + kg * 4 + p) * 6144L + 4096 + h * 128 + db * 8);
    }
    lds_barrier();

    fx4 s[4];
#pragma unroll
    for (int nf = 0; nf < 4; ++nf) s[nf] = fz;
#pragma unroll
    for (int kc = 0; kc < 4; ++kc) {
#pragma unroll
      for (int nf = 0; nf < 4; ++nf) {
        const int rl = nf * 16 + l16;
        bx8 kb = *reinterpret_cast<const bx8*>(smem + rl * 256 + (((kc * 4 + lg) ^ l16) << 4));
        s[nf] = mfma16(qf[kc], kb, s[nf]);
      }
    }

    if (t == qt) {
#pragma unroll
      for (int nf = 0; nf < 4; ++nf) {
        const int kv_abs = t * 64 + nf * 16 + l16;
#pragma unroll
        for (int r = 0; r < 4; ++r) {
          const int q_abs = qb + w * 16 + lg * 4 + r;
          if (kv_abs > q_abs) s[nf][r] = -3e38f;
        }
      }
    }

    float rm_[4];
    bool st = true;
#pragma unroll
    for (int r = 0; r < 4; ++r) {
      float rm = fmaxf(fmaxf(s[0][r], s[1][r]), fmaxf(s[2][r], s[3][r]));
      rm_[r] = rowmax16(rm);
      st = st && (rm_[r] - m_r[r] <= 62.7f);
    }
    float pv[4][4];
    if (__all(st ? 1 : 0)) {
#pragma unroll
      for (int r = 0; r < 4; ++r) {
        float rs = 0.f;
#pragma unroll
        for (int nf = 0; nf < 4; ++nf) {
          const float p = exp2f((s[nf][r] - m_r[r]) * sc2);
          pv[nf][r] = p;
          rs += p;
        }
        l_r[r] += rowsum16(rs);
      }
    } else {
#pragma unroll
      for (int r = 0; r < 4; ++r) {
        const float mn = fmaxf(m_r[r], rm_[r]);
        const float fac = exp2f((m_r[r] - mn) * sc2);
        m_r[r] = mn;
        float rs = 0.f;
#pragma unroll
        for (int nf = 0; nf < 4; ++nf) {
          const float p = exp2f((s[nf][r] - mn) * sc2);
          pv[nf][r] = p;
          rs += p;
        }
        l_r[r] = l_r[r] * fac + rowsum16(rs);
#pragma unroll
        for (int nf = 0; nf < 8; ++nf) o_acc[nf][r] *= fac;
      }
    }

#pragma unroll
    for (int nf = 0; nf < 4; ++nf)
#pragma unroll
      for (int r = 0; r < 4; ++r) {
        const int ro = lg * 4 + r;
        *reinterpret_cast<unsigned short*>(
            psb + ro * 128 + (((nf * 2 + (l16 >> 3)) ^ (ro & 7)) << 4) + ((l16 & 7) << 1)) =
            __builtin_bit_cast(unsigned short, (__bf16)pv[nf][r]);
      }

    bx8 pa[2];
#pragma unroll
    for (int kc = 0; kc < 2; ++kc)
      pa[kc] = *reinterpret_cast<const bx8*>(psb + l16 * 128 + (((kc * 4 + lg) ^ (l16 & 7)) << 4));

#pragma unroll
    for (int nf = 0; nf < 8; ++nf) {
#pragma unroll
      for (int kc = 0; kc < 2; ++kc) {
        bx8 vb = *reinterpret_cast<const bx8*>(smem + 16384 + (nf * 16 + l16) * 128 +
                                               (((kc * 4 + lg) ^ (l16 & 7)) << 4));
        o_acc[nf] = mfma16(pa[kc], vb, o_acc[nf]);
      }
    }
  }

  unsigned short* ob = Obuf + (long)id * 8192;
#pragma unroll
  for (int nf = 0; nf < 8; ++nf)
#pragma unroll
    for (int r = 0; r < 4; ++r) {
      const int row = w * 16 + lg * 4 + r;
      ob[row * 128 + nf * 16 + l16] = f2bf(o_acc[nf][r]);
    }
  if (l16 == 0) {
#pragma unroll
    for (int r = 0; r < 4; ++r) {
      const int row = w * 16 + lg * 4 + r;
      ML[((long)id * 64 + row) * 2 + 0] = m_r[r];
      ML[((long)id * 64 + row) * 2 + 1] = l_r[r];
    }
  }
}

// ---------- combine <=4 chunk partials into attnb (R11-proven) ----------
__global__ __launch_bounds__(256) void fa_combine(const unsigned short* __restrict__ Obuf,
                                                  const float* __restrict__ ML,
                                                  unsigned short* __restrict__ out) {
  const int p = blockIdx.x;
  const int qt = p >> 4, h = p & 15;
  const int nc = (qt + 8) >> 3;
  const int tid = threadIdx.x;
  const int row = tid >> 2;
  const int c0 = (tid & 3) * 32;
  const float sc2 = 0.1275173831f;

  int ids[4];
#pragma unroll
  for (int k = 0; k < 4; ++k) {
    int ib;
    if (qt >= 24)      ib = (31 - qt) * 4 + k;
    else if (qt >= 16) ib = 32 + (23 - qt) * 3 + k;
    else if (qt >= 8)  ib = 56 + (15 - qt) * 2 + k;
    else               ib = 72 + (7 - qt);
    ids[k] = ib * 16 + h;
  }

  float mk[4], lk[4];
  float m = -3e38f;
#pragma unroll
  for (int k = 0; k < 4; ++k)
    if (k < nc) {
      mk[k] = ML[((long)ids[k] * 64 + row) * 2 + 0];
      lk[k] = ML[((long)ids[k] * 64 + row) * 2 + 1];
      m = fmaxf(m, mk[k]);
    }
  float fk[4], denom = 0.f;
#pragma unroll
  for (int k = 0; k < 4; ++k)
    if (k < nc) {
      fk[k] = exp2f((mk[k] - m) * sc2);
      denom += lk[k] * fk[k];
    }
  const float inv = 1.0f / denom;

  float acc[32];
#pragma unroll
  for (int j = 0; j < 32; ++j) acc[j] = 0.f;
#pragma unroll
  for (int k = 0; k < 4; ++k)
    if (k < nc) {
      const unsigned short* ob = Obuf + (long)ids[k] * 8192 + row * 128 + c0;
      const float f = fk[k];
#pragma unroll
      for (int jj = 0; jj < 4; ++jj) {
        us8 a = *reinterpret_cast<const us8*>(ob + jj * 8);
#pragma unroll
        for (int j2 = 0; j2 < 8; ++j2) acc[jj * 8 + j2] += bf2f(a[j2]) * f;
      }
    }

  unsigned short* dst = out + (long)(qt * 64 + row) * 2048 + h * 128 + c0;
#pragma unroll
  for (int jj = 0; jj < 4; ++jj) {
    ushort4 o0, o1;
    o0.x = f2bf(acc[jj * 8 + 0] * inv);
    o0.y = f2bf(acc[jj * 8 + 1] * inv);
    o0.z = f2bf(acc[jj * 8 + 2] * inv);
    o0.w = f2bf(acc[jj * 8 + 3] * inv);
    o1.x = f2bf(acc[jj * 8 + 4] * inv);
    o1.y = f2bf(acc[jj * 8 + 5] * inv);
    o1.z = f2bf(acc[jj * 8 + 6] * inv);
    o1.w = f2bf(acc[jj * 8 + 7] * inv);
    *reinterpret_cast<ushort4*>(dst + jj * 8) = o0;
    *reinterpret_cast<ushort4*>(dst + jj * 8 + 4) = o1;
  }
}

// ---------- launch ----------
// Interface (confirmed R4): inputs fp32, output fp32.
// Workspace plan (peak 56 MiB):
//   wab   [0, 24 MiB)     bf16 W_attn (dead after GEMM1)
//   qkvb  [24, 48 MiB)    bf16 qkv (dead after fa)
//   xb    [48, 56 MiB)    bf16 x (dead after GEMM1)
//   -- after GEMM1, overlaying dead regions:
//   Obuf  [0, 20 MiB)     1280 x 64x128 bf16 partial O numerators (dead after combine)
//   ML    [20, 20.625)    1280 x 64 x (m,l) fp32 (dead after combine)
//   attnb [48, 56 MiB)    bf16 attn out (overlays dead xb)
//   -- after combine:
//   wpb   [0, 8 MiB)      bf16 W_proj (overlays dead Obuf)
extern "C" void kernel_launch(void* const* d_in, const int* in_sizes, int n_in,
                              void* d_out, int out_size, void* d_ws, size_t ws_size,
                              hipStream_t stream) {
  const float* x  = (const float*)d_in[0];   // (2048, 2048) fp32
  const float* Wa = (const float*)d_in[1];   // (6144, 2048) fp32
  const float* Wp = (const float*)d_in[2];   // (2048, 2048) fp32
  float* out = (float*)d_out;                // (2048, 2048) fp32
  char* ws = (char*)d_ws;

  unsigned short* wab   = (unsigned short*)(ws);                 // 24 MiB
  unsigned short* qkvb  = (unsigned short*)(ws + (24ull << 20)); // 24 MiB
  unsigned short* xb    = (unsigned short*)(ws + (48ull << 20)); //  8 MiB
  unsigned short* Obuf  = (unsigned short*)(ws);                 // 20 MiB (after GEMM1)
  float*          ML    = (float*)(ws + (20ull << 20));          // 640 KiB (after GEMM1)
  unsigned short* attnb = (unsigned short*)(ws + (48ull << 20)); //  8 MiB (after GEMM1)
  unsigned short* wpb   = (unsigned short*)(ws);                 //  8 MiB (after combine)

  f2b_kernel<<<4096, 256, 0, stream>>>(x, xb, 2048 * 2048);
  f2b_kernel<<<12288, 256, 0, stream>>>(Wa, wab, 6144 * 2048);

  // qkv = x @ W_attn^T : M=2048, N=6144, K=2048 — deep-pipelined 256^2 kernel
  gemm256<<<dim3(24, 8), 512, 0, stream>>>(xb, wab, qkvb, 2048, 6144, 2048);

  // causal flash attention: 1280 uniform 8-tile chunk items (heavy first)
  fa_kernel<<<1280, 256, 0, stream>>>(qkvb, Obuf, ML);

  // merge 1..4 chunk partials per (qt, h)
  fa_combine<<<512, 256, 0, stream>>>(Obuf, ML, attnb);

  // W_proj convert into region freed by Obuf (stream-ordered after combine)
  f2b_kernel<<<4096, 256, 0, stream>>>(Wp, wpb, 2048 * 2048);

  // out = attn @ W_proj^T : M=2048, N=2048, K=2048 — counted-vmcnt 128^2 pipeline, fp32 out
  gemm2p<<<dim3(16, 16), 256, 0, stream>>>(attnb, wpb, out, 2048, 2048, 2048);
}

// Round 18
// 180.440 us; speedup vs baseline: 1.0210x; 1.0185x over previous
//
#include <hip/hip_runtime.h>
#include <cstdint>

// ---------- types ----------
using bx8 = __attribute__((ext_vector_type(8))) __bf16;   // MFMA A/B fragment (8 bf16)
using us8 = __attribute__((ext_vector_type(8))) unsigned short;
using us4 = __attribute__((ext_vector_type(4))) unsigned short;
using fl8 = __attribute__((ext_vector_type(8))) float;
using fx4 = __attribute__((ext_vector_type(4))) float;    // MFMA C/D fragment

static __device__ inline unsigned short f2bf(float f) {
  unsigned u = __builtin_bit_cast(unsigned, f);
  unsigned r = 0x7FFFu + ((u >> 16) & 1u);   // round-to-nearest-even
  return (unsigned short)((u + r) >> 16);
}
static __device__ inline float bf2f(unsigned short s) {
  return __builtin_bit_cast(float, (unsigned)s << 16);
}

static __device__ inline fx4 mfma16(bx8 a, bx8 b, fx4 c) {
  return __builtin_amdgcn_mfma_f32_16x16x32_bf16(a, b, c, 0, 0, 0);
}

// async global->LDS, 16B/lane; dest = wave-uniform base + lane*16 (R9-proven w/ drain)
static __device__ inline void gload16(const void* g, void* lds) {
  __builtin_amdgcn_global_load_lds(
      (const __attribute__((address_space(1))) void*)g,
      (__attribute__((address_space(3))) void*)lds,
      16, 0, 0);
}
#define VMCNT(n) asm volatile("s_waitcnt vmcnt(" #n ")" ::: "memory")
// raw barrier (does NOT drain vmcnt, unlike __syncthreads) + compiler fences
static __device__ inline void wave_barrier() {
  __builtin_amdgcn_sched_barrier(0);
  __builtin_amdgcn_s_barrier();
  __builtin_amdgcn_sched_barrier(0);
}
// LDS-only barrier: drains lgkmcnt but NOT vmcnt.
static __device__ inline void lds_barrier() {
  __builtin_amdgcn_sched_barrier(0);
  asm volatile("s_waitcnt lgkmcnt(0)" ::: "memory");
  __builtin_amdgcn_s_barrier();
  __builtin_amdgcn_sched_barrier(0);
}

// DPP row_ror:k (VALU-latency cross-lane)
#define DPP_ROR(x, k) __builtin_bit_cast(float, __builtin_amdgcn_update_dpp( \
    __builtin_bit_cast(int, x), __builtin_bit_cast(int, x), 0x120 | (k), 0xF, 0xF, false))

static __device__ inline float rowmax16(float v) {
  v = fmaxf(v, DPP_ROR(v, 1));
  v = fmaxf(v, DPP_ROR(v, 2));
  v = fmaxf(v, DPP_ROR(v, 4));
  v = fmaxf(v, DPP_ROR(v, 8));
  return v;
}
static __device__ inline float rowsum16(float v) {
  v += DPP_ROR(v, 1);
  v += DPP_ROR(v, 2);
  v += DPP_ROR(v, 4);
  v += DPP_ROR(v, 8);
  return v;
}

// ---------- fp32 -> bf16 convert (R4-proven) ----------
__global__ __launch_bounds__(256) void f2b_kernel(const float* __restrict__ in,
                                                  unsigned short* __restrict__ out,
                                                  int n) {
  int i = (blockIdx.x * 256 + threadIdx.x) * 4;
  if (i >= n) return;
  float4 v = *reinterpret_cast<const float4*>(in + i);
  ushort4 o;
  o.x = f2bf(v.x); o.y = f2bf(v.y); o.z = f2bf(v.z); o.w = f2bf(v.w);
  *reinterpret_cast<ushort4*>(out + i) = o;
}

// ================= GEMM1: 256x256 tile, BK=32, depth-3 counted-vmcnt pipeline (R10/R15-proven) =================
__global__ __launch_bounds__(512, 2) void gemm256(const unsigned short* __restrict__ A,
                                                  const unsigned short* __restrict__ B,
                                                  unsigned short* __restrict__ C,
                                                  int M, int N, int K) {
  __shared__ unsigned short lds[4][2][256 * 32];   // [buf][A/B][row*32 + col]

  const int tid = threadIdx.x;
  const int w = tid >> 6, l = tid & 63;
  const int l16 = l & 15, lg = l >> 4;
  const int wr = w >> 2, wc = w & 3;
  const long mb = (long)blockIdx.y * 256, nb = (long)blockIdx.x * 256;

  const int lr = l >> 2;
  const int sw = (((l & 3) ^ (lr & 3)) * 8);       // pre-swizzled col (elements)
  const unsigned short* Ag = A + (mb + w * 32 + lr) * (long)K + sw;
  const unsigned short* Bg = B + (nb + w * 32 + lr) * (long)K + sw;

  const int rdcol = ((lg ^ (l16 & 3)) * 16);

  const fx4 fz = {0.f, 0.f, 0.f, 0.f};
  fx4 acc[8][4];
#pragma unroll
  for (int i = 0; i < 8; ++i)
#pragma unroll
    for (int j = 0; j < 4; ++j) acc[i][j] = fz;

  const int nt = K >> 5;   // K/32 tiles

  auto stage = [&](int tp) {
    const int db = tp & 3;
    const unsigned short* as = Ag + tp * 32;
    const unsigned short* bs = Bg + tp * 32;
    char* al = (char*)&lds[db][0][0] + w * 32 * 64;
    char* bl = (char*)&lds[db][1][0] + w * 32 * 64;
    gload16(as, al);
    gload16(as + 16 * (long)K, al + 1024);
    gload16(bs, bl);
    gload16(bs + 16 * (long)K, bl + 1024);
  };

  auto compute = [&](int bt) {
    const char* Ab = (const char*)&lds[bt][0][0] + (wr * 128 + l16) * 64 + rdcol;
    const char* Bb = (const char*)&lds[bt][1][0] + (wc * 64 + l16) * 64 + rdcol;
    bx8 bf[4];
#pragma unroll
    for (int nf = 0; nf < 4; ++nf)
      bf[nf] = *reinterpret_cast<const bx8*>(Bb + nf * 1024);
    __builtin_amdgcn_s_setprio(1);
#pragma unroll
    for (int mf = 0; mf < 8; ++mf) {
      bx8 av = *reinterpret_cast<const bx8*>(Ab + mf * 1024);
#pragma unroll
      for (int nf = 0; nf < 4; ++nf)
        acc[mf][nf] = mfma16(av, bf[nf], acc[mf][nf]);
    }
    __builtin_amdgcn_s_setprio(0);
  };

  stage(0); stage(1); stage(2);
  VMCNT(8);
  wave_barrier();

  int t = 0;
  for (; t < nt - 3; ++t) {
    stage(t + 3);
    compute(t & 3);
    VMCNT(8);
    wave_barrier();
  }
  compute(t & 3); VMCNT(4); wave_barrier(); ++t;
  compute(t & 3); VMCNT(0); wave_barrier(); ++t;
  compute(t & 3);

#pragma unroll
  for (int mf = 0; mf < 8; ++mf)
#pragma unroll
    for (int nf = 0; nf < 4; ++nf)
#pragma unroll
      for (int r = 0; r < 4; ++r) {
        const long row = mb + wr * 128 + mf * 16 + lg * 4 + r;
        const long col = nb + wc * 64 + nf * 16 + l16;
        C[row * N + col] = f2bf(acc[mf][nf][r]);
      }
}

// ---------- staging-reg type per operand dtype (R8-proven fold GEMM) ----------
template <typename T> struct RegOf { using type = us8; };
template <> struct RegOf<float>  { using type = fl8; };

template <typename T>
static __device__ inline typename RegOf<T>::type load8(const T* p) {
  return *reinterpret_cast<const typename RegOf<T>::type*>(p);
}
static __device__ inline us8 toBf(us8 v) { return v; }
static __device__ inline us8 toBf(fl8 f) {
  us8 o;
#pragma unroll
  for (int j = 0; j < 8; ++j) {
    __bf16 b = (__bf16)f[j];
    o[j] = __builtin_bit_cast(unsigned short, b);
  }
  return o;
}

// ---------- GEMM2: R8/R15-proven 128x128 reg-staged fold kernel + vmcnt-free barriers ----------
template <typename TA, typename TB, bool F32OUT>
__global__ __launch_bounds__(256) void gemm_bt(const TA* __restrict__ A,
                                               const TB* __restrict__ B,
                                               void* __restrict__ Cp,
                                               int M, int N, int K) {
  __shared__ alignas(16) unsigned short As[128 * 64];
  __shared__ alignas(16) unsigned short Bs[128 * 64];
  const int tid = threadIdx.x;
  const int w = tid >> 6, l = tid & 63;
  const int l16 = l & 15, lg = l >> 4;
  const int wr = w >> 1, wc = w & 1;
  const long mb = (long)blockIdx.y * 128, nb = (long)blockIdx.x * 128;

  const fx4 fz = {0.f, 0.f, 0.f, 0.f};
  fx4 acc[4][4];
#pragma unroll
  for (int i = 0; i < 4; ++i)
#pragma unroll
    for (int j = 0; j < 4; ++j) acc[i][j] = fz;

  const int sr  = tid >> 3;
  const int sc8 = (tid & 7) * 8;
  const int wbc = sc8 * 2;

  typename RegOf<TA>::type rA[4];
  typename RegOf<TB>::type rB[4];

#pragma unroll
  for (int p = 0; p < 4; ++p) {
    const int row = p * 32 + sr;
    rA[p] = load8(A + (mb + row) * (long)K + sc8);
    rB[p] = load8(B + (nb + row) * (long)K + sc8);
  }

  for (int k0 = 0; k0 < K; k0 += 64) {
    lds_barrier();   // prior iter's LDS reads done (no vmcnt drain)
#pragma unroll
    for (int p = 0; p < 4; ++p) {
      const int row = p * 32 + sr;
      const int eo = row * 64 + ((wbc ^ ((row & 7) << 4)) >> 1);
      *reinterpret_cast<us8*>(&As[eo]) = toBf(rA[p]);
      *reinterpret_cast<us8*>(&Bs[eo]) = toBf(rB[p]);
    }
    if (k0 + 64 < K) {
#pragma unroll
      for (int p = 0; p < 4; ++p) {
        const int row = p * 32 + sr;
        rA[p] = load8(A + (mb + row) * (long)K + k0 + 64 + sc8);
        rB[p] = load8(B + (nb + row) * (long)K + k0 + 64 + sc8);
      }
    }
    lds_barrier();   // tiles resident; prefetch loads stay in flight
#pragma unroll
    for (int kk = 0; kk < 2; ++kk) {
      bx8 a[4], b[4];
#pragma unroll
      for (int mf = 0; mf < 4; ++mf) {
        const int ra = wr * 64 + mf * 16 + l16;
        const int bc = kk * 64 + lg * 16;
        a[mf] = *reinterpret_cast<const bx8*>(&As[ra * 64 + ((bc ^ ((ra & 7) << 4)) >> 1)]);
      }
#pragma unroll
      for (int nf = 0; nf < 4; ++nf) {
        const int rb_ = wc * 64 + nf * 16 + l16;
        const int bc = kk * 64 + lg * 16;
        b[nf] = *reinterpret_cast<const bx8*>(&Bs[rb_ * 64 + ((bc ^ ((rb_ & 7) << 4)) >> 1)]);
      }
#pragma unroll
      for (int mf = 0; mf < 4; ++mf)
#pragma unroll
        for (int nf = 0; nf < 4; ++nf)
          acc[mf][nf] = mfma16(a[mf], b[nf], acc[mf][nf]);
    }
  }

#pragma unroll
  for (int mf = 0; mf < 4; ++mf)
#pragma unroll
    for (int nf = 0; nf < 4; ++nf)
#pragma unroll
      for (int r = 0; r < 4; ++r) {
        const long row = mb + wr * 64 + mf * 16 + lg * 4 + r;
        const long col = nb + wc * 64 + nf * 16 + l16;
        if (F32OUT)
          ((float*)Cp)[row * N + col] = acc[mf][nf][r];
        else
          ((unsigned short*)Cp)[row * N + col] = f2bf(acc[mf][nf][r]);
      }
}

// ---------- flash attention (causal) — R18: double-buffered K/V, ONE barrier/step ----------
// smem: buf b (b=0,1): Ks [64r][256B] swz row&15 @ b*32768; Vt [128r][128B] swz row&7
//       @ b*32768+16384; Ps 4 x [16r][128B] @ 65536. Total 72 KiB (2 blocks/CU).
// Iteration t: {ds_write staged regs -> buf[t&1]; issue t+1 loads; lds_barrier;
// compute from buf[t&1]}. Hazards sealed by collective barrier + per-wave lgkm
// drain (see round theory). Everything else identical to the R13/R15-proven body.
__global__ __launch_bounds__(256) void fa_kernel(const unsigned short* __restrict__ qkv,
                                                 unsigned short* __restrict__ Obuf,
                                                 float* __restrict__ ML) {
  __shared__ alignas(16) char smem[73728];

  const int id = blockIdx.x;
  const int h = id & 15, i = id >> 4;
  int qt, ck;
  if (i < 32)      { qt = 31 - (i >> 2); ck = i & 3; }
  else if (i < 56) { const int j = i - 32; qt = 23 - j / 3; ck = j % 3; }
  else if (i < 72) { const int j = i - 56; qt = 15 - (j >> 1); ck = j & 1; }
  else             { qt = 7 - (i - 72); ck = 0; }
  const int t0 = ck * 8;
  const int t1 = min(t0 + 8, qt + 1);
  const int qb = qt * 64;

  const int tid = threadIdx.x;
  const int w = tid >> 6, l = tid & 63;
  const int l16 = l & 15, lg = l >> 4;
  const fx4 fz = {0.f, 0.f, 0.f, 0.f};

  const int kr = tid >> 4, ksl = tid & 15;
  const int kg = tid & 15, db = tid >> 4;
  const int kc8 = ksl * 8;

  bx8 qf[4];
  {
    const long qrow = qb + w * 16 + l16;
    const unsigned short* qp = qkv + qrow * 6144L + h * 128 + lg * 8;
#pragma unroll
    for (int kc = 0; kc < 4; ++kc)
      qf[kc] = *reinterpret_cast<const bx8*>(qp + kc * 32);
  }

  fx4 o_acc[8];
#pragma unroll
  for (int i2 = 0; i2 < 8; ++i2) o_acc[i2] = fz;
  float m_r[4] = {-3e38f, -3e38f, -3e38f, -3e38f};
  float l_r[4] = {0.f, 0.f, 0.f, 0.f};

  us8 rK[4], rV[4];
  {
    const long kvb = (long)t0 * 64;
#pragma unroll
    for (int p = 0; p < 4; ++p)
      rK[p] = *reinterpret_cast<const us8*>(qkv + (kvb + p * 16 + kr) * 6144L + 2048 + h * 128 + kc8);
#pragma unroll
    for (int p = 0; p < 4; ++p)
      rV[p] = *reinterpret_cast<const us8*>(qkv + (kvb + kg * 4 + p) * 6144L + 4096 + h * 128 + db * 8);
  }

  const float sc2 = 0.1275173831f;  // (1/sqrt(128)) * log2(e)
  char* const psb = smem + 65536 + w * 2048;

  for (int t = t0; t < t1; ++t) {
    char* const buf = smem + (((t - t0) & 1) << 15);   // 0 or 32768

    // write staged K (4 x b128), swizzled: slot' = ksl ^ kr
#pragma unroll
    for (int p = 0; p < 4; ++p)
      *reinterpret_cast<us8*>(buf + (p * 16 + kr) * 256 + ((ksl ^ kr) << 4)) = rK[p];
    // write staged V transposed (8 x b64), swizzled
#pragma unroll
    for (int j = 0; j < 8; ++j) {
      us4 vw = {rV[0][j], rV[1][j], rV[2][j], rV[3][j]};
      *reinterpret_cast<us4*>(buf + 16384 + (db * 8 + j) * 128 +
                              (((kg >> 1) ^ j) << 4) + ((kg & 1) << 3)) = vw;
    }

    // issue loads for tile t+1 — in flight across the barrier
    if (t + 1 < t1) {
      const long kvb = (long)(t + 1) * 64;
#pragma unroll
      for (int p = 0; p < 4; ++p)
        rK[p] = *reinterpret_cast<const us8*>(qkv + (kvb + p * 16 + kr) * 6144L + 2048 + h * 128 + kc8);
#pragma unroll
      for (int p = 0; p < 4; ++p)
        rV[p] = *reinterpret_cast<const us8*>(qkv + (kvb + kg * 4 + p) * 6144L + 4096 + h * 128 + db * 8);
    }

    lds_barrier();   // the ONLY barrier per step: writes visible, prior reads sealed

    // --- S = Q * K^T  (16 q x 64 kv per wave) ---
    fx4 s[4];
#pragma unroll
    for (int nf = 0; nf < 4; ++nf) s[nf] = fz;
#pragma unroll
    for (int kc = 0; kc < 4; ++kc) {
#pragma unroll
      for (int nf = 0; nf < 4; ++nf) {
        const int rl = nf * 16 + l16;
        bx8 kb = *reinterpret_cast<const bx8*>(buf + rl * 256 + (((kc * 4 + lg) ^ l16) << 4));
        s[nf] = mfma16(qf[kc], kb, s[nf]);
      }
    }

    // --- causal mask (possible only on tile t == qt) ---
    if (t == qt) {
#pragma unroll
      for (int nf = 0; nf < 4; ++nf) {
        const int kv_abs = t * 64 + nf * 16 + l16;
#pragma unroll
        for (int r = 0; r < 4; ++r) {
          const int q_abs = qb + w * 16 + lg * 4 + r;
          if (kv_abs > q_abs) s[nf][r] = -3e38f;
        }
      }
    }

    // --- online softmax with defer-rescale (T13) ---
    float rm_[4];
    bool st = true;
#pragma unroll
    for (int r = 0; r < 4; ++r) {
      float rm = fmaxf(fmaxf(s[0][r], s[1][r]), fmaxf(s[2][r], s[3][r]));
      rm_[r] = rowmax16(rm);
      st = st && (rm_[r] - m_r[r] <= 62.7f);
    }
    float pv[4][4];
    if (__all(st ? 1 : 0)) {
#pragma unroll
      for (int r = 0; r < 4; ++r) {
        float rs = 0.f;
#pragma unroll
        for (int nf = 0; nf < 4; ++nf) {
          const float p = exp2f((s[nf][r] - m_r[r]) * sc2);
          pv[nf][r] = p;
          rs += p;
        }
        l_r[r] += rowsum16(rs);
      }
    } else {
#pragma unroll
      for (int r = 0; r < 4; ++r) {
        const float mn = fmaxf(m_r[r], rm_[r]);
        const float fac = exp2f((m_r[r] - mn) * sc2);
        m_r[r] = mn;
        float rs = 0.f;
#pragma unroll
        for (int nf = 0; nf < 4; ++nf) {
          const float p = exp2f((s[nf][r] - mn) * sc2);
          pv[nf][r] = p;
          rs += p;
        }
        l_r[r] = l_r[r] * fac + rowsum16(rs);
#pragma unroll
        for (int nf = 0; nf < 8; ++nf) o_acc[nf][r] *= fac;
      }
    }

    // --- P -> per-wave LDS (swizzled) -> A-fragments (same-wave, lgkm-ordered) ---
#pragma unroll
    for (int nf = 0; nf < 4; ++nf)
#pragma unroll
      for (int r = 0; r < 4; ++r) {
        const int ro = lg * 4 + r;
        *reinterpret_cast<unsigned short*>(
            psb + ro * 128 + (((nf * 2 + (l16 >> 3)) ^ (ro & 7)) << 4) + ((l16 & 7) << 1)) =
            __builtin_bit_cast(unsigned short, (__bf16)pv[nf][r]);
      }

    bx8 pa[2];
#pragma unroll
    for (int kc = 0; kc < 2; ++kc)
      pa[kc] = *reinterpret_cast<const bx8*>(psb + l16 * 128 + (((kc * 4 + lg) ^ (l16 & 7)) << 4));

    // --- O += P * V ---
#pragma unroll
    for (int nf = 0; nf < 8; ++nf) {
#pragma unroll
      for (int kc = 0; kc < 2; ++kc) {
        bx8 vb = *reinterpret_cast<const bx8*>(buf + 16384 + (nf * 16 + l16) * 128 +
                                               (((kc * 4 + lg) ^ (l16 & 7)) << 4));
        o_acc[nf] = mfma16(pa[kc], vb, o_acc[nf]);
      }
    }
  }

  unsigned short* ob = Obuf + (long)id * 8192;
#pragma unroll
  for (int nf = 0; nf < 8; ++nf)
#pragma unroll
    for (int r = 0; r < 4; ++r) {
      const int row = w * 16 + lg * 4 + r;
      ob[row * 128 + nf * 16 + l16] = f2bf(o_acc[nf][r]);
    }
  if (l16 == 0) {
#pragma unroll
    for (int r = 0; r < 4; ++r) {
      const int row = w * 16 + lg * 4 + r;
      ML[((long)id * 64 + row) * 2 + 0] = m_r[r];
      ML[((long)id * 64 + row) * 2 + 1] = l_r[r];
    }
  }
}

// ---------- combine <=4 chunk partials into attnb (R11-proven) ----------
__global__ __launch_bounds__(256) void fa_combine(const unsigned short* __restrict__ Obuf,
                                                  const float* __restrict__ ML,
                                                  unsigned short* __restrict__ out) {
  const int p = blockIdx.x;
  const int qt = p >> 4, h = p & 15;
  const int nc = (qt + 8) >> 3;
  const int tid = threadIdx.x;
  const int row = tid >> 2;
  const int c0 = (tid & 3) * 32;
  const float sc2 = 0.1275173831f;

  int ids[4];
#pragma unroll
  for (int k = 0; k < 4; ++k) {
    int ib;
    if (qt >= 24)      ib = (31 - qt) * 4 + k;
    else if (qt >= 16) ib = 32 + (23 - qt) * 3 + k;
    else if (qt >= 8)  ib = 56 + (15 - qt) * 2 + k;
    else               ib = 72 + (7 - qt);
    ids[k] = ib * 16 + h;
  }

  float mk[4], lk[4];
  float m = -3e38f;
#pragma unroll
  for (int k = 0; k < 4; ++k)
    if (k < nc) {
      mk[k] = ML[((long)ids[k] * 64 + row) * 2 + 0];
      lk[k] = ML[((long)ids[k] * 64 + row) * 2 + 1];
      m = fmaxf(m, mk[k]);
    }
  float fk[4], denom = 0.f;
#pragma unroll
  for (int k = 0; k < 4; ++k)
    if (k < nc) {
      fk[k] = exp2f((mk[k] - m) * sc2);
      denom += lk[k] * fk[k];
    }
  const float inv = 1.0f / denom;

  float acc[32];
#pragma unroll
  for (int j = 0; j < 32; ++j) acc[j] = 0.f;
#pragma unroll
  for (int k = 0; k < 4; ++k)
    if (k < nc) {
      const unsigned short* ob = Obuf + (long)ids[k] * 8192 + row * 128 + c0;
      const float f = fk[k];
#pragma unroll
      for (int jj = 0; jj < 4; ++jj) {
        us8 a = *reinterpret_cast<const us8*>(ob + jj * 8);
#pragma unroll
        for (int j2 = 0; j2 < 8; ++j2) acc[jj * 8 + j2] += bf2f(a[j2]) * f;
      }
    }

  unsigned short* dst = out + (long)(qt * 64 + row) * 2048 + h * 128 + c0;
#pragma unroll
  for (int jj = 0; jj < 4; ++jj) {
    ushort4 o0, o1;
    o0.x = f2bf(acc[jj * 8 + 0] * inv);
    o0.y = f2bf(acc[jj * 8 + 1] * inv);
    o0.z = f2bf(acc[jj * 8 + 2] * inv);
    o0.w = f2bf(acc[jj * 8 + 3] * inv);
    o1.x = f2bf(acc[jj * 8 + 4] * inv);
    o1.y = f2bf(acc[jj * 8 + 5] * inv);
    o1.z = f2bf(acc[jj * 8 + 6] * inv);
    o1.w = f2bf(acc[jj * 8 + 7] * inv);
    *reinterpret_cast<ushort4*>(dst + jj * 8) = o0;
    *reinterpret_cast<ushort4*>(dst + jj * 8 + 4) = o1;
  }
}

// ---------- launch ----------
// Interface (confirmed R4): inputs fp32, output fp32.
// Workspace plan (peak 56 MiB):
//   wab   [0, 24 MiB)     bf16 W_attn (dead after GEMM1)
//   qkvb  [24, 48 MiB)    bf16 qkv
//   xb    [48, 56 MiB)    bf16 x (dead after GEMM1)
//   -- after GEMM1, overlaying dead regions:
//   Obuf  [0, 20 MiB)     1280 x 64x128 bf16 partial O numerators
//   ML    [20, 20.625)    1280 x 64 x (m,l) fp32
//   attnb [48, 56 MiB)    bf16 attn out (overlays dead xb)
extern "C" void kernel_launch(void* const* d_in, const int* in_sizes, int n_in,
                              void* d_out, int out_size, void* d_ws, size_t ws_size,
                              hipStream_t stream) {
  const float* x  = (const float*)d_in[0];   // (2048, 2048) fp32
  const float* Wa = (const float*)d_in[1];   // (6144, 2048) fp32
  const float* Wp = (const float*)d_in[2];   // (2048, 2048) fp32
  float* out = (float*)d_out;                // (2048, 2048) fp32
  char* ws = (char*)d_ws;

  unsigned short* wab   = (unsigned short*)(ws);                 // 24 MiB
  unsigned short* qkvb  = (unsigned short*)(ws + (24ull << 20)); // 24 MiB
  unsigned short* xb    = (unsigned short*)(ws + (48ull << 20)); //  8 MiB
  unsigned short* Obuf  = (unsigned short*)(ws);                 // 20 MiB (after GEMM1)
  float*          ML    = (float*)(ws + (20ull << 20));          // 640 KiB (after GEMM1)
  unsigned short* attnb = (unsigned short*)(ws + (48ull << 20)); //  8 MiB (after GEMM1)

  f2b_kernel<<<4096, 256, 0, stream>>>(x, xb, 2048 * 2048);
  f2b_kernel<<<12288, 256, 0, stream>>>(Wa, wab, 6144 * 2048);

  // qkv = x @ W_attn^T : M=2048, N=6144, K=2048 — deep-pipelined 256^2 kernel
  gemm256<<<dim3(24, 8), 512, 0, stream>>>(xb, wab, qkvb, 2048, 6144, 2048);

  // causal flash attention: 1280 uniform 8-tile chunk items (heavy first)
  fa_kernel<<<1280, 256, 0, stream>>>(qkvb, Obuf, ML);

  // merge 1..4 chunk partials per (qt, h)
  fa_combine<<<512, 256, 0, stream>>>(Obuf, ML, attnb);

  // out = attn @ W_proj^T : M=2048, N=2048, K=2048 (A bf16, B fp32 fold, fp32 out)
  gemm_bt<unsigned short, float, true><<<dim3(16, 16), 256, 0, stream>>>(attnb, Wp, (void*)out, 2048, 2048, 2048);
}

// Round 19
// 177.387 us; speedup vs baseline: 1.0386x; 1.0172x over previous
//
#include <hip/hip_runtime.h>
#include <cstdint>

// ---------- types ----------
using bx8 = __attribute__((ext_vector_type(8))) __bf16;   // MFMA A/B fragment (8 bf16)
using us8 = __attribute__((ext_vector_type(8))) unsigned short;
using us4 = __attribute__((ext_vector_type(4))) unsigned short;
using fl8 = __attribute__((ext_vector_type(8))) float;
using fx4 = __attribute__((ext_vector_type(4))) float;    // MFMA C/D fragment

static __device__ inline unsigned short f2bf(float f) {
  unsigned u = __builtin_bit_cast(unsigned, f);
  unsigned r = 0x7FFFu + ((u >> 16) & 1u);   // round-to-nearest-even
  return (unsigned short)((u + r) >> 16);
}
static __device__ inline float bf2f(unsigned short s) {
  return __builtin_bit_cast(float, (unsigned)s << 16);
}

static __device__ inline fx4 mfma16(bx8 a, bx8 b, fx4 c) {
  return __builtin_amdgcn_mfma_f32_16x16x32_bf16(a, b, c, 0, 0, 0);
}

// async global->LDS, 16B/lane; dest = wave-uniform base + lane*16 (R9-proven w/ drain)
static __device__ inline void gload16(const void* g, void* lds) {
  __builtin_amdgcn_global_load_lds(
      (const __attribute__((address_space(1))) void*)g,
      (__attribute__((address_space(3))) void*)lds,
      16, 0, 0);
}
#define VMCNT(n) asm volatile("s_waitcnt vmcnt(" #n ")" ::: "memory")
// raw barrier (does NOT drain vmcnt, unlike __syncthreads) + compiler fences
static __device__ inline void wave_barrier() {
  __builtin_amdgcn_sched_barrier(0);
  __builtin_amdgcn_s_barrier();
  __builtin_amdgcn_sched_barrier(0);
}
// LDS-only barrier: drains lgkmcnt but NOT vmcnt.
static __device__ inline void lds_barrier() {
  __builtin_amdgcn_sched_barrier(0);
  asm volatile("s_waitcnt lgkmcnt(0)" ::: "memory");
  __builtin_amdgcn_s_barrier();
  __builtin_amdgcn_sched_barrier(0);
}

// DPP row_ror:k (VALU-latency cross-lane)
#define DPP_ROR(x, k) __builtin_bit_cast(float, __builtin_amdgcn_update_dpp( \
    __builtin_bit_cast(int, x), __builtin_bit_cast(int, x), 0x120 | (k), 0xF, 0xF, false))

static __device__ inline float rowmax16(float v) {
  v = fmaxf(v, DPP_ROR(v, 1));
  v = fmaxf(v, DPP_ROR(v, 2));
  v = fmaxf(v, DPP_ROR(v, 4));
  v = fmaxf(v, DPP_ROR(v, 8));
  return v;
}
static __device__ inline float rowsum16(float v) {
  v += DPP_ROR(v, 1);
  v += DPP_ROR(v, 2);
  v += DPP_ROR(v, 4);
  v += DPP_ROR(v, 8);
  return v;
}

// ---------- fp32 -> bf16 convert (R4-proven) ----------
__global__ __launch_bounds__(256) void f2b_kernel(const float* __restrict__ in,
                                                  unsigned short* __restrict__ out,
                                                  int n) {
  int i = (blockIdx.x * 256 + threadIdx.x) * 4;
  if (i >= n) return;
  float4 v = *reinterpret_cast<const float4*>(in + i);
  ushort4 o;
  o.x = f2bf(v.x); o.y = f2bf(v.y); o.z = f2bf(v.z); o.w = f2bf(v.w);
  *reinterpret_cast<ushort4*>(out + i) = o;
}

// ================= GEMM1: 256x256 tile, BK=32, depth-3 counted-vmcnt pipeline =================
// R19: swizzle key fixed (row&3 -> (row>>1)&3). Old key collapsed the four
// same-(l16&3) lanes of each bank-parity class onto ONE slot -> 4-way ds_read
// conflict (the measured 4.7e6). New key maps even-l16 lanes to slots
// {0,1,2,3,0,1,2,3} -> 2-way = free (m136). Write/read use the same involution:
// key(row) = (row>>1)&3; all row bases are multiples of 8 so key reduces to
// (lr>>1)&3 on the write side and (l16>>1)&3 on the read side.
__global__ __launch_bounds__(512, 2) void gemm256(const unsigned short* __restrict__ A,
                                                  const unsigned short* __restrict__ B,
                                                  unsigned short* __restrict__ C,
                                                  int M, int N, int K) {
  __shared__ unsigned short lds[4][2][256 * 32];   // [buf][A/B][row*32 + col]

  const int tid = threadIdx.x;
  const int w = tid >> 6, l = tid & 63;
  const int l16 = l & 15, lg = l >> 4;
  const int wr = w >> 2, wc = w & 3;
  const long mb = (long)blockIdx.y * 256, nb = (long)blockIdx.x * 256;

  const int lr = l >> 2;
  const int sw = (((l & 3) ^ ((lr >> 1) & 3)) * 8);   // pre-swizzled col (elements)
  const unsigned short* Ag = A + (mb + w * 32 + lr) * (long)K + sw;
  const unsigned short* Bg = B + (nb + w * 32 + lr) * (long)K + sw;

  const int rdcol = ((lg ^ ((l16 >> 1) & 3)) * 16);   // matching read swizzle

  const fx4 fz = {0.f, 0.f, 0.f, 0.f};
  fx4 acc[8][4];
#pragma unroll
  for (int i = 0; i < 8; ++i)
#pragma unroll
    for (int j = 0; j < 4; ++j) acc[i][j] = fz;

  const int nt = K >> 5;   // K/32 tiles

  auto stage = [&](int tp) {
    const int db = tp & 3;
    const unsigned short* as = Ag + tp * 32;
    const unsigned short* bs = Bg + tp * 32;
    char* al = (char*)&lds[db][0][0] + w * 32 * 64;
    char* bl = (char*)&lds[db][1][0] + w * 32 * 64;
    gload16(as, al);
    gload16(as + 16 * (long)K, al + 1024);
    gload16(bs, bl);
    gload16(bs + 16 * (long)K, bl + 1024);
  };

  auto compute = [&](int bt) {
    const char* Ab = (const char*)&lds[bt][0][0] + (wr * 128 + l16) * 64 + rdcol;
    const char* Bb = (const char*)&lds[bt][1][0] + (wc * 64 + l16) * 64 + rdcol;
    bx8 bf[4];
#pragma unroll
    for (int nf = 0; nf < 4; ++nf)
      bf[nf] = *reinterpret_cast<const bx8*>(Bb + nf * 1024);
    __builtin_amdgcn_s_setprio(1);
#pragma unroll
    for (int mf = 0; mf < 8; ++mf) {
      bx8 av = *reinterpret_cast<const bx8*>(Ab + mf * 1024);
#pragma unroll
      for (int nf = 0; nf < 4; ++nf)
        acc[mf][nf] = mfma16(av, bf[nf], acc[mf][nf]);
    }
    __builtin_amdgcn_s_setprio(0);
  };

  stage(0); stage(1); stage(2);
  VMCNT(8);
  wave_barrier();

  int t = 0;
  for (; t < nt - 3; ++t) {
    stage(t + 3);
    compute(t & 3);
    VMCNT(8);
    wave_barrier();
  }
  compute(t & 3); VMCNT(4); wave_barrier(); ++t;
  compute(t & 3); VMCNT(0); wave_barrier(); ++t;
  compute(t & 3);

#pragma unroll
  for (int mf = 0; mf < 8; ++mf)
#pragma unroll
    for (int nf = 0; nf < 4; ++nf)
#pragma unroll
      for (int r = 0; r < 4; ++r) {
        const long row = mb + wr * 128 + mf * 16 + lg * 4 + r;
        const long col = nb + wc * 64 + nf * 16 + l16;
        C[row * N + col] = f2bf(acc[mf][nf][r]);
      }
}

// ---------- staging-reg type per operand dtype (R8-proven fold GEMM) ----------
template <typename T> struct RegOf { using type = us8; };
template <> struct RegOf<float>  { using type = fl8; };

template <typename T>
static __device__ inline typename RegOf<T>::type load8(const T* p) {
  return *reinterpret_cast<const typename RegOf<T>::type*>(p);
}
static __device__ inline us8 toBf(us8 v) { return v; }
static __device__ inline us8 toBf(fl8 f) {
  us8 o;
#pragma unroll
  for (int j = 0; j < 8; ++j) {
    __bf16 b = (__bf16)f[j];
    o[j] = __builtin_bit_cast(unsigned short, b);
  }
  return o;
}

// ---------- GEMM2: R8/R15-proven 128x128 reg-staged fold kernel + vmcnt-free barriers ----------
template <typename TA, typename TB, bool F32OUT>
__global__ __launch_bounds__(256) void gemm_bt(const TA* __restrict__ A,
                                               const TB* __restrict__ B,
                                               void* __restrict__ Cp,
                                               int M, int N, int K) {
  __shared__ alignas(16) unsigned short As[128 * 64];
  __shared__ alignas(16) unsigned short Bs[128 * 64];
  const int tid = threadIdx.x;
  const int w = tid >> 6, l = tid & 63;
  const int l16 = l & 15, lg = l >> 4;
  const int wr = w >> 1, wc = w & 1;
  const long mb = (long)blockIdx.y * 128, nb = (long)blockIdx.x * 128;

  const fx4 fz = {0.f, 0.f, 0.f, 0.f};
  fx4 acc[4][4];
#pragma unroll
  for (int i = 0; i < 4; ++i)
#pragma unroll
    for (int j = 0; j < 4; ++j) acc[i][j] = fz;

  const int sr  = tid >> 3;
  const int sc8 = (tid & 7) * 8;
  const int wbc = sc8 * 2;

  typename RegOf<TA>::type rA[4];
  typename RegOf<TB>::type rB[4];

#pragma unroll
  for (int p = 0; p < 4; ++p) {
    const int row = p * 32 + sr;
    rA[p] = load8(A + (mb + row) * (long)K + sc8);
    rB[p] = load8(B + (nb + row) * (long)K + sc8);
  }

  for (int k0 = 0; k0 < K; k0 += 64) {
    lds_barrier();   // prior iter's LDS reads done (no vmcnt drain)
#pragma unroll
    for (int p = 0; p < 4; ++p) {
      const int row = p * 32 + sr;
      const int eo = row * 64 + ((wbc ^ ((row & 7) << 4)) >> 1);
      *reinterpret_cast<us8*>(&As[eo]) = toBf(rA[p]);
      *reinterpret_cast<us8*>(&Bs[eo]) = toBf(rB[p]);
    }
    if (k0 + 64 < K) {
#pragma unroll
      for (int p = 0; p < 4; ++p) {
        const int row = p * 32 + sr;
        rA[p] = load8(A + (mb + row) * (long)K + k0 + 64 + sc8);
        rB[p] = load8(B + (nb + row) * (long)K + k0 + 64 + sc8);
      }
    }
    lds_barrier();   // tiles resident; prefetch loads stay in flight
#pragma unroll
    for (int kk = 0; kk < 2; ++kk) {
      bx8 a[4], b[4];
#pragma unroll
      for (int mf = 0; mf < 4; ++mf) {
        const int ra = wr * 64 + mf * 16 + l16;
        const int bc = kk * 64 + lg * 16;
        a[mf] = *reinterpret_cast<const bx8*>(&As[ra * 64 + ((bc ^ ((ra & 7) << 4)) >> 1)]);
      }
#pragma unroll
      for (int nf = 0; nf < 4; ++nf) {
        const int rb_ = wc * 64 + nf * 16 + l16;
        const int bc = kk * 64 + lg * 16;
        b[nf] = *reinterpret_cast<const bx8*>(&Bs[rb_ * 64 + ((bc ^ ((rb_ & 7) << 4)) >> 1)]);
      }
#pragma unroll
      for (int mf = 0; mf < 4; ++mf)
#pragma unroll
        for (int nf = 0; nf < 4; ++nf)
          acc[mf][nf] = mfma16(a[mf], b[nf], acc[mf][nf]);
    }
  }

#pragma unroll
  for (int mf = 0; mf < 4; ++mf)
#pragma unroll
    for (int nf = 0; nf < 4; ++nf)
#pragma unroll
      for (int r = 0; r < 4; ++r) {
        const long row = mb + wr * 64 + mf * 16 + lg * 4 + r;
        const long col = nb + wc * 64 + nf * 16 + l16;
        if (F32OUT)
          ((float*)Cp)[row * N + col] = acc[mf][nf][r];
        else
          ((unsigned short*)Cp)[row * N + col] = f2bf(acc[mf][nf][r]);
      }
}

// ---------- flash attention (causal) — R18-proven: double-buffered K/V, one barrier/step ----------
__global__ __launch_bounds__(256) void fa_kernel(const unsigned short* __restrict__ qkv,
                                                 unsigned short* __restrict__ Obuf,
                                                 float* __restrict__ ML) {
  __shared__ alignas(16) char smem[73728];

  const int id = blockIdx.x;
  const int h = id & 15, i = id >> 4;
  int qt, ck;
  if (i < 32)      { qt = 31 - (i >> 2); ck = i & 3; }
  else if (i < 56) { const int j = i - 32; qt = 23 - j / 3; ck = j % 3; }
  else if (i < 72) { const int j = i - 56; qt = 15 - (j >> 1); ck = j & 1; }
  else             { qt = 7 - (i - 72); ck = 0; }
  const int t0 = ck * 8;
  const int t1 = min(t0 + 8, qt + 1);
  const int qb = qt * 64;

  const int tid = threadIdx.x;
  const int w = tid >> 6, l = tid & 63;
  const int l16 = l & 15, lg = l >> 4;
  const fx4 fz = {0.f, 0.f, 0.f, 0.f};

  const int kr = tid >> 4, ksl = tid & 15;
  const int kg = tid & 15, db = tid >> 4;
  const int kc8 = ksl * 8;

  bx8 qf[4];
  {
    const long qrow = qb + w * 16 + l16;
    const unsigned short* qp = qkv + qrow * 6144L + h * 128 + lg * 8;
#pragma unroll
    for (int kc = 0; kc < 4; ++kc)
      qf[kc] = *reinterpret_cast<const bx8*>(qp + kc * 32);
  }

  fx4 o_acc[8];
#pragma unroll
  for (int i2 = 0; i2 < 8; ++i2) o_acc[i2] = fz;
  float m_r[4] = {-3e38f, -3e38f, -3e38f, -3e38f};
  float l_r[4] = {0.f, 0.f, 0.f, 0.f};

  us8 rK[4], rV[4];
  {
    const long kvb = (long)t0 * 64;
#pragma unroll
    for (int p = 0; p < 4; ++p)
      rK[p] = *reinterpret_cast<const us8*>(qkv + (kvb + p * 16 + kr) * 6144L + 2048 + h * 128 + kc8);
#pragma unroll
    for (int p = 0; p < 4; ++p)
      rV[p] = *reinterpret_cast<const us8*>(qkv + (kvb + kg * 4 + p) * 6144L + 4096 + h * 128 + db * 8);
  }

  const float sc2 = 0.1275173831f;  // (1/sqrt(128)) * log2(e)
  char* const psb = smem + 65536 + w * 2048;

  for (int t = t0; t < t1; ++t) {
    char* const buf = smem + (((t - t0) & 1) << 15);   // 0 or 32768

#pragma unroll
    for (int p = 0; p < 4; ++p)
      *reinterpret_cast<us8*>(buf + (p * 16 + kr) * 256 + ((ksl ^ kr) << 4)) = rK[p];
#pragma unroll
    for (int j = 0; j < 8; ++j) {
      us4 vw = {rV[0][j], rV[1][j], rV[2][j], rV[3][j]};
      *reinterpret_cast<us4*>(buf + 16384 + (db * 8 + j) * 128 +
                              (((kg >> 1) ^ j) << 4) + ((kg & 1) << 3)) = vw;
    }

    if (t + 1 < t1) {
      const long kvb = (long)(t + 1) * 64;
#pragma unroll
      for (int p = 0; p < 4; ++p)
        rK[p] = *reinterpret_cast<const us8*>(qkv + (kvb + p * 16 + kr) * 6144L + 2048 + h * 128 + kc8);
#pragma unroll
      for (int p = 0; p < 4; ++p)
        rV[p] = *reinterpret_cast<const us8*>(qkv + (kvb + kg * 4 + p) * 6144L + 4096 + h * 128 + db * 8);
    }

    lds_barrier();   // single barrier per step

    fx4 s[4];
#pragma unroll
    for (int nf = 0; nf < 4; ++nf) s[nf] = fz;
#pragma unroll
    for (int kc = 0; kc < 4; ++kc) {
#pragma unroll
      for (int nf = 0; nf < 4; ++nf) {
        const int rl = nf * 16 + l16;
        bx8 kb = *reinterpret_cast<const bx8*>(buf + rl * 256 + (((kc * 4 + lg) ^ l16) << 4));
        s[nf] = mfma16(qf[kc], kb, s[nf]);
      }
    }

    if (t == qt) {
#pragma unroll
      for (int nf = 0; nf < 4; ++nf) {
        const int kv_abs = t * 64 + nf * 16 + l16;
#pragma unroll
        for (int r = 0; r < 4; ++r) {
          const int q_abs = qb + w * 16 + lg * 4 + r;
          if (kv_abs > q_abs) s[nf][r] = -3e38f;
        }
      }
    }

    float rm_[4];
    bool st = true;
#pragma unroll
    for (int r = 0; r < 4; ++r) {
      float rm = fmaxf(fmaxf(s[0][r], s[1][r]), fmaxf(s[2][r], s[3][r]));
      rm_[r] = rowmax16(rm);
      st = st && (rm_[r] - m_r[r] <= 62.7f);
    }
    float pv[4][4];
    if (__all(st ? 1 : 0)) {
#pragma unroll
      for (int r = 0; r < 4; ++r) {
        float rs = 0.f;
#pragma unroll
        for (int nf = 0; nf < 4; ++nf) {
          const float p = exp2f((s[nf][r] - m_r[r]) * sc2);
          pv[nf][r] = p;
          rs += p;
        }
        l_r[r] += rowsum16(rs);
      }
    } else {
#pragma unroll
      for (int r = 0; r < 4; ++r) {
        const float mn = fmaxf(m_r[r], rm_[r]);
        const float fac = exp2f((m_r[r] - mn) * sc2);
        m_r[r] = mn;
        float rs = 0.f;
#pragma unroll
        for (int nf = 0; nf < 4; ++nf) {
          const float p = exp2f((s[nf][r] - mn) * sc2);
          pv[nf][r] = p;
          rs += p;
        }
        l_r[r] = l_r[r] * fac + rowsum16(rs);
#pragma unroll
        for (int nf = 0; nf < 8; ++nf) o_acc[nf][r] *= fac;
      }
    }

#pragma unroll
    for (int nf = 0; nf < 4; ++nf)
#pragma unroll
      for (int r = 0; r < 4; ++r) {
        const int ro = lg * 4 + r;
        *reinterpret_cast<unsigned short*>(
            psb + ro * 128 + (((nf * 2 + (l16 >> 3)) ^ (ro & 7)) << 4) + ((l16 & 7) << 1)) =
            __builtin_bit_cast(unsigned short, (__bf16)pv[nf][r]);
      }

    bx8 pa[2];
#pragma unroll
    for (int kc = 0; kc < 2; ++kc)
      pa[kc] = *reinterpret_cast<const bx8*>(psb + l16 * 128 + (((kc * 4 + lg) ^ (l16 & 7)) << 4));

#pragma unroll
    for (int nf = 0; nf < 8; ++nf) {
#pragma unroll
      for (int kc = 0; kc < 2; ++kc) {
        bx8 vb = *reinterpret_cast<const bx8*>(buf + 16384 + (nf * 16 + l16) * 128 +
                                               (((kc * 4 + lg) ^ (l16 & 7)) << 4));
        o_acc[nf] = mfma16(pa[kc], vb, o_acc[nf]);
      }
    }
  }

  unsigned short* ob = Obuf + (long)id * 8192;
#pragma unroll
  for (int nf = 0; nf < 8; ++nf)
#pragma unroll
    for (int r = 0; r < 4; ++r) {
      const int row = w * 16 + lg * 4 + r;
      ob[row * 128 + nf * 16 + l16] = f2bf(o_acc[nf][r]);
    }
  if (l16 == 0) {
#pragma unroll
    for (int r = 0; r < 4; ++r) {
      const int row = w * 16 + lg * 4 + r;
      ML[((long)id * 64 + row) * 2 + 0] = m_r[r];
      ML[((long)id * 64 + row) * 2 + 1] = l_r[r];
    }
  }
}

// ---------- combine <=4 chunk partials into attnb (R11-proven) ----------
__global__ __launch_bounds__(256) void fa_combine(const unsigned short* __restrict__ Obuf,
                                                  const float* __restrict__ ML,
                                                  unsigned short* __restrict__ out) {
  const int p = blockIdx.x;
  const int qt = p >> 4, h = p & 15;
  const int nc = (qt + 8) >> 3;
  const int tid = threadIdx.x;
  const int row = tid >> 2;
  const int c0 = (tid & 3) * 32;
  const float sc2 = 0.1275173831f;

  int ids[4];
#pragma unroll
  for (int k = 0; k < 4; ++k) {
    int ib;
    if (qt >= 24)      ib = (31 - qt) * 4 + k;
    else if (qt >= 16) ib = 32 + (23 - qt) * 3 + k;
    else if (qt >= 8)  ib = 56 + (15 - qt) * 2 + k;
    else               ib = 72 + (7 - qt);
    ids[k] = ib * 16 + h;
  }

  float mk[4], lk[4];
  float m = -3e38f;
#pragma unroll
  for (int k = 0; k < 4; ++k)
    if (k < nc) {
      mk[k] = ML[((long)ids[k] * 64 + row) * 2 + 0];
      lk[k] = ML[((long)ids[k] * 64 + row) * 2 + 1];
      m = fmaxf(m, mk[k]);
    }
  float fk[4], denom = 0.f;
#pragma unroll
  for (int k = 0; k < 4; ++k)
    if (k < nc) {
      fk[k] = exp2f((mk[k] - m) * sc2);
      denom += lk[k] * fk[k];
    }
  const float inv = 1.0f / denom;

  float acc[32];
#pragma unroll
  for (int j = 0; j < 32; ++j) acc[j] = 0.f;
#pragma unroll
  for (int k = 0; k < 4; ++k)
    if (k < nc) {
      const unsigned short* ob = Obuf + (long)ids[k] * 8192 + row * 128 + c0;
      const float f = fk[k];
#pragma unroll
      for (int jj = 0; jj < 4; ++jj) {
        us8 a = *reinterpret_cast<const us8*>(ob + jj * 8);
#pragma unroll
        for (int j2 = 0; j2 < 8; ++j2) acc[jj * 8 + j2] += bf2f(a[j2]) * f;
      }
    }

  unsigned short* dst = out + (long)(qt * 64 + row) * 2048 + h * 128 + c0;
#pragma unroll
  for (int jj = 0; jj < 4; ++jj) {
    ushort4 o0, o1;
    o0.x = f2bf(acc[jj * 8 + 0] * inv);
    o0.y = f2bf(acc[jj * 8 + 1] * inv);
    o0.z = f2bf(acc[jj * 8 + 2] * inv);
    o0.w = f2bf(acc[jj * 8 + 3] * inv);
    o1.x = f2bf(acc[jj * 8 + 4] * inv);
    o1.y = f2bf(acc[jj * 8 + 5] * inv);
    o1.z = f2bf(acc[jj * 8 + 6] * inv);
    o1.w = f2bf(acc[jj * 8 + 7] * inv);
    *reinterpret_cast<ushort4*>(dst + jj * 8) = o0;
    *reinterpret_cast<ushort4*>(dst + jj * 8 + 4) = o1;
  }
}

// ---------- launch ----------
// Interface (confirmed R4): inputs fp32, output fp32.
// Workspace plan (peak 56 MiB):
//   wab   [0, 24 MiB)     bf16 W_attn (dead after GEMM1)
//   qkvb  [24, 48 MiB)    bf16 qkv
//   xb    [48, 56 MiB)    bf16 x (dead after GEMM1)
//   -- after GEMM1, overlaying dead regions:
//   Obuf  [0, 20 MiB)     1280 x 64x128 bf16 partial O numerators
//   ML    [20, 20.625)    1280 x 64 x (m,l) fp32
//   attnb [48, 56 MiB)    bf16 attn out (overlays dead xb)
extern "C" void kernel_launch(void* const* d_in, const int* in_sizes, int n_in,
                              void* d_out, int out_size, void* d_ws, size_t ws_size,
                              hipStream_t stream) {
  const float* x  = (const float*)d_in[0];   // (2048, 2048) fp32
  const float* Wa = (const float*)d_in[1];   // (6144, 2048) fp32
  const float* Wp = (const float*)d_in[2];   // (2048, 2048) fp32
  float* out = (float*)d_out;                // (2048, 2048) fp32
  char* ws = (char*)d_ws;

  unsigned short* wab   = (unsigned short*)(ws);                 // 24 MiB
  unsigned short* qkvb  = (unsigned short*)(ws + (24ull << 20)); // 24 MiB
  unsigned short* xb    = (unsigned short*)(ws + (48ull << 20)); //  8 MiB
  unsigned short* Obuf  = (unsigned short*)(ws);                 // 20 MiB (after GEMM1)
  float*          ML    = (float*)(ws + (20ull << 20));          // 640 KiB (after GEMM1)
  unsigned short* attnb = (unsigned short*)(ws + (48ull << 20)); //  8 MiB (after GEMM1)

  f2b_kernel<<<4096, 256, 0, stream>>>(x, xb, 2048 * 2048);
  f2b_kernel<<<12288, 256, 0, stream>>>(Wa, wab, 6144 * 2048);

  // qkv = x @ W_attn^T : M=2048, N=6144, K=2048 — deep-pipelined 256^2 kernel
  gemm256<<<dim3(24, 8), 512, 0, stream>>>(xb, wab, qkvb, 2048, 6144, 2048);

  // causal flash attention: 1280 uniform 8-tile chunk items (heavy first)
  fa_kernel<<<1280, 256, 0, stream>>>(qkvb, Obuf, ML);

  // merge 1..4 chunk partials per (qt, h)
  fa_combine<<<512, 256, 0, stream>>>(Obuf, ML, attnb);

  // out = attn @ W_proj^T : M=2048, N=2048, K=2048 (A bf16, B fp32 fold, fp32 out)
  gemm_bt<unsigned short, float, true><<<dim3(16, 16), 256, 0, stream>>>(attnb, Wp, (void*)out, 2048, 2048, 2048);
}

// Round 20
// 174.365 us; speedup vs baseline: 1.0566x; 1.0173x over previous
//
#include <hip/hip_runtime.h>
#include <cstdint>

// ---------- types ----------
using bx8 = __attribute__((ext_vector_type(8))) __bf16;   // MFMA A/B fragment (8 bf16)
using us8 = __attribute__((ext_vector_type(8))) unsigned short;
using us4 = __attribute__((ext_vector_type(4))) unsigned short;
using fl8 = __attribute__((ext_vector_type(8))) float;
using fx4 = __attribute__((ext_vector_type(4))) float;    // MFMA C/D fragment

static __device__ inline unsigned short f2bf(float f) {
  unsigned u = __builtin_bit_cast(unsigned, f);
  unsigned r = 0x7FFFu + ((u >> 16) & 1u);   // round-to-nearest-even
  return (unsigned short)((u + r) >> 16);
}
static __device__ inline float bf2f(unsigned short s) {
  return __builtin_bit_cast(float, (unsigned)s << 16);
}

static __device__ inline fx4 mfma16(bx8 a, bx8 b, fx4 c) {
  return __builtin_amdgcn_mfma_f32_16x16x32_bf16(a, b, c, 0, 0, 0);
}

// async global->LDS, 16B/lane; dest = wave-uniform base + lane*16 (R9-proven w/ drain)
static __device__ inline void gload16(const void* g, void* lds) {
  __builtin_amdgcn_global_load_lds(
      (const __attribute__((address_space(1))) void*)g,
      (__attribute__((address_space(3))) void*)lds,
      16, 0, 0);
}
#define VMCNT(n) asm volatile("s_waitcnt vmcnt(" #n ")" ::: "memory")
// raw barrier (does NOT drain vmcnt, unlike __syncthreads) + compiler fences
static __device__ inline void wave_barrier() {
  __builtin_amdgcn_sched_barrier(0);
  __builtin_amdgcn_s_barrier();
  __builtin_amdgcn_sched_barrier(0);
}
// LDS-only barrier: drains lgkmcnt but NOT vmcnt.
static __device__ inline void lds_barrier() {
  __builtin_amdgcn_sched_barrier(0);
  asm volatile("s_waitcnt lgkmcnt(0)" ::: "memory");
  __builtin_amdgcn_s_barrier();
  __builtin_amdgcn_sched_barrier(0);
}

// DPP row_ror:k (VALU-latency cross-lane)
#define DPP_ROR(x, k) __builtin_bit_cast(float, __builtin_amdgcn_update_dpp( \
    __builtin_bit_cast(int, x), __builtin_bit_cast(int, x), 0x120 | (k), 0xF, 0xF, false))

static __device__ inline float rowmax16(float v) {
  v = fmaxf(v, DPP_ROR(v, 1));
  v = fmaxf(v, DPP_ROR(v, 2));
  v = fmaxf(v, DPP_ROR(v, 4));
  v = fmaxf(v, DPP_ROR(v, 8));
  return v;
}
static __device__ inline float rowsum16(float v) {
  v += DPP_ROR(v, 1);
  v += DPP_ROR(v, 2);
  v += DPP_ROR(v, 4);
  v += DPP_ROR(v, 8);
  return v;
}

// ---------- fp32 -> bf16 convert, two tensors in ONE dispatch (R20) ----------
// i < n1/4 handles in1; otherwise in2 (flat 4-elem chunks).
__global__ __launch_bounds__(256) void f2b2_kernel(const float* __restrict__ in1,
                                                   unsigned short* __restrict__ out1,
                                                   int n1,
                                                   const float* __restrict__ in2,
                                                   unsigned short* __restrict__ out2,
                                                   int n2) {
  int c = blockIdx.x * 256 + threadIdx.x;
  const int c1 = n1 >> 2;
  const float* in;
  unsigned short* out;
  if (c < c1) {
    in = in1; out = out1;
  } else {
    c -= c1;
    if (c >= (n2 >> 2)) return;
    in = in2; out = out2;
  }
  const int i = c * 4;
  float4 v = *reinterpret_cast<const float4*>(in + i);
  ushort4 o;
  o.x = f2bf(v.x); o.y = f2bf(v.y); o.z = f2bf(v.z); o.w = f2bf(v.w);
  *reinterpret_cast<ushort4*>(out + i) = o;
}

// ================= GEMM1: 256x256 tile, BK=32, depth-3 counted-vmcnt pipeline =================
// R19-proven: swizzle key (row>>1)&3 (2-way bank aliasing = free, m136).
__global__ __launch_bounds__(512, 2) void gemm256(const unsigned short* __restrict__ A,
                                                  const unsigned short* __restrict__ B,
                                                  unsigned short* __restrict__ C,
                                                  int M, int N, int K) {
  __shared__ unsigned short lds[4][2][256 * 32];   // [buf][A/B][row*32 + col]

  const int tid = threadIdx.x;
  const int w = tid >> 6, l = tid & 63;
  const int l16 = l & 15, lg = l >> 4;
  const int wr = w >> 2, wc = w & 3;
  const long mb = (long)blockIdx.y * 256, nb = (long)blockIdx.x * 256;

  const int lr = l >> 2;
  const int sw = (((l & 3) ^ ((lr >> 1) & 3)) * 8);   // pre-swizzled col (elements)
  const unsigned short* Ag = A + (mb + w * 32 + lr) * (long)K + sw;
  const unsigned short* Bg = B + (nb + w * 32 + lr) * (long)K + sw;

  const int rdcol = ((lg ^ ((l16 >> 1) & 3)) * 16);   // matching read swizzle

  const fx4 fz = {0.f, 0.f, 0.f, 0.f};
  fx4 acc[8][4];
#pragma unroll
  for (int i = 0; i < 8; ++i)
#pragma unroll
    for (int j = 0; j < 4; ++j) acc[i][j] = fz;

  const int nt = K >> 5;   // K/32 tiles

  auto stage = [&](int tp) {
    const int db = tp & 3;
    const unsigned short* as = Ag + tp * 32;
    const unsigned short* bs = Bg + tp * 32;
    char* al = (char*)&lds[db][0][0] + w * 32 * 64;
    char* bl = (char*)&lds[db][1][0] + w * 32 * 64;
    gload16(as, al);
    gload16(as + 16 * (long)K, al + 1024);
    gload16(bs, bl);
    gload16(bs + 16 * (long)K, bl + 1024);
  };

  auto compute = [&](int bt) {
    const char* Ab = (const char*)&lds[bt][0][0] + (wr * 128 + l16) * 64 + rdcol;
    const char* Bb = (const char*)&lds[bt][1][0] + (wc * 64 + l16) * 64 + rdcol;
    bx8 bf[4];
#pragma unroll
    for (int nf = 0; nf < 4; ++nf)
      bf[nf] = *reinterpret_cast<const bx8*>(Bb + nf * 1024);
    __builtin_amdgcn_s_setprio(1);
#pragma unroll
    for (int mf = 0; mf < 8; ++mf) {
      bx8 av = *reinterpret_cast<const bx8*>(Ab + mf * 1024);
#pragma unroll
      for (int nf = 0; nf < 4; ++nf)
        acc[mf][nf] = mfma16(av, bf[nf], acc[mf][nf]);
    }
    __builtin_amdgcn_s_setprio(0);
  };

  stage(0); stage(1); stage(2);
  VMCNT(8);
  wave_barrier();

  int t = 0;
  for (; t < nt - 3; ++t) {
    stage(t + 3);
    compute(t & 3);
    VMCNT(8);
    wave_barrier();
  }
  compute(t & 3); VMCNT(4); wave_barrier(); ++t;
  compute(t & 3); VMCNT(0); wave_barrier(); ++t;
  compute(t & 3);

#pragma unroll
  for (int mf = 0; mf < 8; ++mf)
#pragma unroll
    for (int nf = 0; nf < 4; ++nf)
#pragma unroll
      for (int r = 0; r < 4; ++r) {
        const long row = mb + wr * 128 + mf * 16 + lg * 4 + r;
        const long col = nb + wc * 64 + nf * 16 + l16;
        C[row * N + col] = f2bf(acc[mf][nf][r]);
      }
}

// ---------- staging-reg type per operand dtype (R8-proven fold GEMM) ----------
template <typename T> struct RegOf { using type = us8; };
template <> struct RegOf<float>  { using type = fl8; };

template <typename T>
static __device__ inline typename RegOf<T>::type load8(const T* p) {
  return *reinterpret_cast<const typename RegOf<T>::type*>(p);
}
static __device__ inline us8 toBf(us8 v) { return v; }
static __device__ inline us8 toBf(fl8 f) {
  us8 o;
#pragma unroll
  for (int j = 0; j < 8; ++j) {
    __bf16 b = (__bf16)f[j];
    o[j] = __builtin_bit_cast(unsigned short, b);
  }
  return o;
}

// ---------- GEMM2: R8/R15-proven 128x128 reg-staged fold kernel + vmcnt-free barriers ----------
template <typename TA, typename TB, bool F32OUT>
__global__ __launch_bounds__(256) void gemm_bt(const TA* __restrict__ A,
                                               const TB* __restrict__ B,
                                               void* __restrict__ Cp,
                                               int M, int N, int K) {
  __shared__ alignas(16) unsigned short As[128 * 64];
  __shared__ alignas(16) unsigned short Bs[128 * 64];
  const int tid = threadIdx.x;
  const int w = tid >> 6, l = tid & 63;
  const int l16 = l & 15, lg = l >> 4;
  const int wr = w >> 1, wc = w & 1;
  const long mb = (long)blockIdx.y * 128, nb = (long)blockIdx.x * 128;

  const fx4 fz = {0.f, 0.f, 0.f, 0.f};
  fx4 acc[4][4];
#pragma unroll
  for (int i = 0; i < 4; ++i)
#pragma unroll
    for (int j = 0; j < 4; ++j) acc[i][j] = fz;

  const int sr  = tid >> 3;
  const int sc8 = (tid & 7) * 8;
  const int wbc = sc8 * 2;

  typename RegOf<TA>::type rA[4];
  typename RegOf<TB>::type rB[4];

#pragma unroll
  for (int p = 0; p < 4; ++p) {
    const int row = p * 32 + sr;
    rA[p] = load8(A + (mb + row) * (long)K + sc8);
    rB[p] = load8(B + (nb + row) * (long)K + sc8);
  }

  for (int k0 = 0; k0 < K; k0 += 64) {
    lds_barrier();   // prior iter's LDS reads done (no vmcnt drain)
#pragma unroll
    for (int p = 0; p < 4; ++p) {
      const int row = p * 32 + sr;
      const int eo = row * 64 + ((wbc ^ ((row & 7) << 4)) >> 1);
      *reinterpret_cast<us8*>(&As[eo]) = toBf(rA[p]);
      *reinterpret_cast<us8*>(&Bs[eo]) = toBf(rB[p]);
    }
    if (k0 + 64 < K) {
#pragma unroll
      for (int p = 0; p < 4; ++p) {
        const int row = p * 32 + sr;
        rA[p] = load8(A + (mb + row) * (long)K + k0 + 64 + sc8);
        rB[p] = load8(B + (nb + row) * (long)K + k0 + 64 + sc8);
      }
    }
    lds_barrier();   // tiles resident; prefetch loads stay in flight
#pragma unroll
    for (int kk = 0; kk < 2; ++kk) {
      bx8 a[4], b[4];
#pragma unroll
      for (int mf = 0; mf < 4; ++mf) {
        const int ra = wr * 64 + mf * 16 + l16;
        const int bc = kk * 64 + lg * 16;
        a[mf] = *reinterpret_cast<const bx8*>(&As[ra * 64 + ((bc ^ ((ra & 7) << 4)) >> 1)]);
      }
#pragma unroll
      for (int nf = 0; nf < 4; ++nf) {
        const int rb_ = wc * 64 + nf * 16 + l16;
        const int bc = kk * 64 + lg * 16;
        b[nf] = *reinterpret_cast<const bx8*>(&Bs[rb_ * 64 + ((bc ^ ((rb_ & 7) << 4)) >> 1)]);
      }
#pragma unroll
      for (int mf = 0; mf < 4; ++mf)
#pragma unroll
        for (int nf = 0; nf < 4; ++nf)
          acc[mf][nf] = mfma16(a[mf], b[nf], acc[mf][nf]);
    }
  }

#pragma unroll
  for (int mf = 0; mf < 4; ++mf)
#pragma unroll
    for (int nf = 0; nf < 4; ++nf)
#pragma unroll
      for (int r = 0; r < 4; ++r) {
        const long row = mb + wr * 64 + mf * 16 + lg * 4 + r;
        const long col = nb + wc * 64 + nf * 16 + l16;
        if (F32OUT)
          ((float*)Cp)[row * N + col] = acc[mf][nf][r];
        else
          ((unsigned short*)Cp)[row * N + col] = f2bf(acc[mf][nf][r]);
      }
}

// ---------- flash attention (causal) — R18-proven: double-buffered K/V, one barrier/step ----------
__global__ __launch_bounds__(256) void fa_kernel(const unsigned short* __restrict__ qkv,
                                                 unsigned short* __restrict__ Obuf,
                                                 float* __restrict__ ML) {
  __shared__ alignas(16) char smem[73728];

  const int id = blockIdx.x;
  const int h = id & 15, i = id >> 4;
  int qt, ck;
  if (i < 32)      { qt = 31 - (i >> 2); ck = i & 3; }
  else if (i < 56) { const int j = i - 32; qt = 23 - j / 3; ck = j % 3; }
  else if (i < 72) { const int j = i - 56; qt = 15 - (j >> 1); ck = j & 1; }
  else             { qt = 7 - (i - 72); ck = 0; }
  const int t0 = ck * 8;
  const int t1 = min(t0 + 8, qt + 1);
  const int qb = qt * 64;

  const int tid = threadIdx.x;
  const int w = tid >> 6, l = tid & 63;
  const int l16 = l & 15, lg = l >> 4;
  const fx4 fz = {0.f, 0.f, 0.f, 0.f};

  const int kr = tid >> 4, ksl = tid & 15;
  const int kg = tid & 15, db = tid >> 4;
  const int kc8 = ksl * 8;

  bx8 qf[4];
  {
    const long qrow = qb + w * 16 + l16;
    const unsigned short* qp = qkv + qrow * 6144L + h * 128 + lg * 8;
#pragma unroll
    for (int kc = 0; kc < 4; ++kc)
      qf[kc] = *reinterpret_cast<const bx8*>(qp + kc * 32);
  }

  fx4 o_acc[8];
#pragma unroll
  for (int i2 = 0; i2 < 8; ++i2) o_acc[i2] = fz;
  float m_r[4] = {-3e38f, -3e38f, -3e38f, -3e38f};
  float l_r[4] = {0.f, 0.f, 0.f, 0.f};

  us8 rK[4], rV[4];
  {
    const long kvb = (long)t0 * 64;
#pragma unroll
    for (int p = 0; p < 4; ++p)
      rK[p] = *reinterpret_cast<const us8*>(qkv + (kvb + p * 16 + kr) * 6144L + 2048 + h * 128 + kc8);
#pragma unroll
    for (int p = 0; p < 4; ++p)
      rV[p] = *reinterpret_cast<const us8*>(qkv + (kvb + kg * 4 + p) * 6144L + 4096 + h * 128 + db * 8);
  }

  const float sc2 = 0.1275173831f;  // (1/sqrt(128)) * log2(e)
  char* const psb = smem + 65536 + w * 2048;

  for (int t = t0; t < t1; ++t) {
    char* const buf = smem + (((t - t0) & 1) << 15);   // 0 or 32768

#pragma unroll
    for (int p = 0; p < 4; ++p)
      *reinterpret_cast<us8*>(buf + (p * 16 + kr) * 256 + ((ksl ^ kr) << 4)) = rK[p];
#pragma unroll
    for (int j = 0; j < 8; ++j) {
      us4 vw = {rV[0][j], rV[1][j], rV[2][j], rV[3][j]};
      *reinterpret_cast<us4*>(buf + 16384 + (db * 8 + j) * 128 +
                              (((kg >> 1) ^ j) << 4) + ((kg & 1) << 3)) = vw;
    }

    if (t + 1 < t1) {
      const long kvb = (long)(t + 1) * 64;
#pragma unroll
      for (int p = 0; p < 4; ++p)
        rK[p] = *reinterpret_cast<const us8*>(qkv + (kvb + p * 16 + kr) * 6144L + 2048 + h * 128 + kc8);
#pragma unroll
      for (int p = 0; p < 4; ++p)
        rV[p] = *reinterpret_cast<const us8*>(qkv + (kvb + kg * 4 + p) * 6144L + 4096 + h * 128 + db * 8);
    }

    lds_barrier();   // single barrier per step

    fx4 s[4];
#pragma unroll
    for (int nf = 0; nf < 4; ++nf) s[nf] = fz;
#pragma unroll
    for (int kc = 0; kc < 4; ++kc) {
#pragma unroll
      for (int nf = 0; nf < 4; ++nf) {
        const int rl = nf * 16 + l16;
        bx8 kb = *reinterpret_cast<const bx8*>(buf + rl * 256 + (((kc * 4 + lg) ^ l16) << 4));
        s[nf] = mfma16(qf[kc], kb, s[nf]);
      }
    }

    if (t == qt) {
#pragma unroll
      for (int nf = 0; nf < 4; ++nf) {
        const int kv_abs = t * 64 + nf * 16 + l16;
#pragma unroll
        for (int r = 0; r < 4; ++r) {
          const int q_abs = qb + w * 16 + lg * 4 + r;
          if (kv_abs > q_abs) s[nf][r] = -3e38f;
        }
      }
    }

    float rm_[4];
    bool st = true;
#pragma unroll
    for (int r = 0; r < 4; ++r) {
      float rm = fmaxf(fmaxf(s[0][r], s[1][r]), fmaxf(s[2][r], s[3][r]));
      rm_[r] = rowmax16(rm);
      st = st && (rm_[r] - m_r[r] <= 62.7f);
    }
    float pv[4][4];
    if (__all(st ? 1 : 0)) {
#pragma unroll
      for (int r = 0; r < 4; ++r) {
        float rs = 0.f;
#pragma unroll
        for (int nf = 0; nf < 4; ++nf) {
          const float p = exp2f((s[nf][r] - m_r[r]) * sc2);
          pv[nf][r] = p;
          rs += p;
        }
        l_r[r] += rowsum16(rs);
      }
    } else {
#pragma unroll
      for (int r = 0; r < 4; ++r) {
        const float mn = fmaxf(m_r[r], rm_[r]);
        const float fac = exp2f((m_r[r] - mn) * sc2);
        m_r[r] = mn;
        float rs = 0.f;
#pragma unroll
        for (int nf = 0; nf < 4; ++nf) {
          const float p = exp2f((s[nf][r] - mn) * sc2);
          pv[nf][r] = p;
          rs += p;
        }
        l_r[r] = l_r[r] * fac + rowsum16(rs);
#pragma unroll
        for (int nf = 0; nf < 8; ++nf) o_acc[nf][r] *= fac;
      }
    }

#pragma unroll
    for (int nf = 0; nf < 4; ++nf)
#pragma unroll
      for (int r = 0; r < 4; ++r) {
        const int ro = lg * 4 + r;
        *reinterpret_cast<unsigned short*>(
            psb + ro * 128 + (((nf * 2 + (l16 >> 3)) ^ (ro & 7)) << 4) + ((l16 & 7) << 1)) =
            __builtin_bit_cast(unsigned short, (__bf16)pv[nf][r]);
      }

    bx8 pa[2];
#pragma unroll
    for (int kc = 0; kc < 2; ++kc)
      pa[kc] = *reinterpret_cast<const bx8*>(psb + l16 * 128 + (((kc * 4 + lg) ^ (l16 & 7)) << 4));

#pragma unroll
    for (int nf = 0; nf < 8; ++nf) {
#pragma unroll
      for (int kc = 0; kc < 2; ++kc) {
        bx8 vb = *reinterpret_cast<const bx8*>(buf + 16384 + (nf * 16 + l16) * 128 +
                                               (((kc * 4 + lg) ^ (l16 & 7)) << 4));
        o_acc[nf] = mfma16(pa[kc], vb, o_acc[nf]);
      }
    }
  }

  unsigned short* ob = Obuf + (long)id * 8192;
#pragma unroll
  for (int nf = 0; nf < 8; ++nf)
#pragma unroll
    for (int r = 0; r < 4; ++r) {
      const int row = w * 16 + lg * 4 + r;
      ob[row * 128 + nf * 16 + l16] = f2bf(o_acc[nf][r]);
    }
  if (l16 == 0) {
#pragma unroll
    for (int r = 0; r < 4; ++r) {
      const int row = w * 16 + lg * 4 + r;
      ML[((long)id * 64 + row) * 2 + 0] = m_r[r];
      ML[((long)id * 64 + row) * 2 + 1] = l_r[r];
    }
  }
}

// ---------- combine <=4 chunk partials into attnb (R11-proven) ----------
__global__ __launch_bounds__(256) void fa_combine(const unsigned short* __restrict__ Obuf,
                                                  const float* __restrict__ ML,
                                                  unsigned short* __restrict__ out) {
  const int p = blockIdx.x;
  const int qt = p >> 4, h = p & 15;
  const int nc = (qt + 8) >> 3;
  const int tid = threadIdx.x;
  const int row = tid >> 2;
  const int c0 = (tid & 3) * 32;
  const float sc2 = 0.1275173831f;

  int ids[4];
#pragma unroll
  for (int k = 0; k < 4; ++k) {
    int ib;
    if (qt >= 24)      ib = (31 - qt) * 4 + k;
    else if (qt >= 16) ib = 32 + (23 - qt) * 3 + k;
    else if (qt >= 8)  ib = 56 + (15 - qt) * 2 + k;
    else               ib = 72 + (7 - qt);
    ids[k] = ib * 16 + h;
  }

  float mk[4], lk[4];
  float m = -3e38f;
#pragma unroll
  for (int k = 0; k < 4; ++k)
    if (k < nc) {
      mk[k] = ML[((long)ids[k] * 64 + row) * 2 + 0];
      lk[k] = ML[((long)ids[k] * 64 + row) * 2 + 1];
      m = fmaxf(m, mk[k]);
    }
  float fk[4], denom = 0.f;
#pragma unroll
  for (int k = 0; k < 4; ++k)
    if (k < nc) {
      fk[k] = exp2f((mk[k] - m) * sc2);
      denom += lk[k] * fk[k];
    }
  const float inv = 1.0f / denom;

  float acc[32];
#pragma unroll
  for (int j = 0; j < 32; ++j) acc[j] = 0.f;
#pragma unroll
  for (int k = 0; k < 4; ++k)
    if (k < nc) {
      const unsigned short* ob = Obuf + (long)ids[k] * 8192 + row * 128 + c0;
      const float f = fk[k];
#pragma unroll
      for (int jj = 0; jj < 4; ++jj) {
        us8 a = *reinterpret_cast<const us8*>(ob + jj * 8);
#pragma unroll
        for (int j2 = 0; j2 < 8; ++j2) acc[jj * 8 + j2] += bf2f(a[j2]) * f;
      }
    }

  unsigned short* dst = out + (long)(qt * 64 + row) * 2048 + h * 128 + c0;
#pragma unroll
  for (int jj = 0; jj < 4; ++jj) {
    ushort4 o0, o1;
    o0.x = f2bf(acc[jj * 8 + 0] * inv);
    o0.y = f2bf(acc[jj * 8 + 1] * inv);
    o0.z = f2bf(acc[jj * 8 + 2] * inv);
    o0.w = f2bf(acc[jj * 8 + 3] * inv);
    o1.x = f2bf(acc[jj * 8 + 4] * inv);
    o1.y = f2bf(acc[jj * 8 + 5] * inv);
    o1.z = f2bf(acc[jj * 8 + 6] * inv);
    o1.w = f2bf(acc[jj * 8 + 7] * inv);
    *reinterpret_cast<ushort4*>(dst + jj * 8) = o0;
    *reinterpret_cast<ushort4*>(dst + jj * 8 + 4) = o1;
  }
}

// ---------- launch ----------
// Interface (confirmed R4): inputs fp32, output fp32.
// Workspace plan (peak 56 MiB):
//   wab   [0, 24 MiB)     bf16 W_attn (dead after GEMM1)
//   qkvb  [24, 48 MiB)    bf16 qkv
//   xb    [48, 56 MiB)    bf16 x (dead after GEMM1)
//   -- after GEMM1, overlaying dead regions:
//   Obuf  [0, 20 MiB)     1280 x 64x128 bf16 partial O numerators
//   ML    [20, 20.625)    1280 x 64 x (m,l) fp32
//   attnb [48, 56 MiB)    bf16 attn out (overlays dead xb)
extern "C" void kernel_launch(void* const* d_in, const int* in_sizes, int n_in,
                              void* d_out, int out_size, void* d_ws, size_t ws_size,
                              hipStream_t stream) {
  const float* x  = (const float*)d_in[0];   // (2048, 2048) fp32
  const float* Wa = (const float*)d_in[1];   // (6144, 2048) fp32
  const float* Wp = (const float*)d_in[2];   // (2048, 2048) fp32
  float* out = (float*)d_out;                // (2048, 2048) fp32
  char* ws = (char*)d_ws;

  unsigned short* wab   = (unsigned short*)(ws);                 // 24 MiB
  unsigned short* qkvb  = (unsigned short*)(ws + (24ull << 20)); // 24 MiB
  unsigned short* xb    = (unsigned short*)(ws + (48ull << 20)); //  8 MiB
  unsigned short* Obuf  = (unsigned short*)(ws);                 // 20 MiB (after GEMM1)
  float*          ML    = (float*)(ws + (20ull << 20));          // 640 KiB (after GEMM1)
  unsigned short* attnb = (unsigned short*)(ws + (48ull << 20)); //  8 MiB (after GEMM1)

  // x and W_attn fp32->bf16 in ONE dispatch (4M + 12M elems = 16384 blocks)
  f2b2_kernel<<<16384, 256, 0, stream>>>(x, xb, 2048 * 2048, Wa, wab, 6144 * 2048);

  // qkv = x @ W_attn^T : M=2048, N=6144, K=2048 — deep-pipelined 256^2 kernel
  gemm256<<<dim3(24, 8), 512, 0, stream>>>(xb, wab, qkvb, 2048, 6144, 2048);

  // causal flash attention: 1280 uniform 8-tile chunk items (heavy first)
  fa_kernel<<<1280, 256, 0, stream>>>(qkvb, Obuf, ML);

  // merge 1..4 chunk partials per (qt, h)
  fa_combine<<<512, 256, 0, stream>>>(Obuf, ML, attnb);

  // out = attn @ W_proj^T : M=2048, N=2048, K=2048 (A bf16, B fp32 fold, fp32 out)
  gemm_bt<unsigned short, float, true><<<dim3(16, 16), 256, 0, stream>>>(attnb, Wp, (void*)out, 2048, 2048, 2048);
}

// Round 21
// 174.012 us; speedup vs baseline: 1.0588x; 1.0020x over previous
//
#include <hip/hip_runtime.h>
#include <cstdint>

// ---------- types ----------
using bx8 = __attribute__((ext_vector_type(8))) __bf16;   // MFMA A/B fragment (8 bf16)
using us8 = __attribute__((ext_vector_type(8))) unsigned short;
using us4 = __attribute__((ext_vector_type(4))) unsigned short;
using fl8 = __attribute__((ext_vector_type(8))) float;
using fx4 = __attribute__((ext_vector_type(4))) float;    // MFMA C/D fragment

static __device__ inline unsigned short f2bf(float f) {
  unsigned u = __builtin_bit_cast(unsigned, f);
  unsigned r = 0x7FFFu + ((u >> 16) & 1u);   // round-to-nearest-even
  return (unsigned short)((u + r) >> 16);
}
static __device__ inline float bf2f(unsigned short s) {
  return __builtin_bit_cast(float, (unsigned)s << 16);
}

static __device__ inline fx4 mfma16(bx8 a, bx8 b, fx4 c) {
  return __builtin_amdgcn_mfma_f32_16x16x32_bf16(a, b, c, 0, 0, 0);
}

// async global->LDS, 16B/lane; dest = wave-uniform base + lane*16 (R9-proven w/ drain)
static __device__ inline void gload16(const void* g, void* lds) {
  __builtin_amdgcn_global_load_lds(
      (const __attribute__((address_space(1))) void*)g,
      (__attribute__((address_space(3))) void*)lds,
      16, 0, 0);
}
#define VMCNT(n) asm volatile("s_waitcnt vmcnt(" #n ")" ::: "memory")
// raw barrier (does NOT drain vmcnt, unlike __syncthreads) + compiler fences
static __device__ inline void wave_barrier() {
  __builtin_amdgcn_sched_barrier(0);
  __builtin_amdgcn_s_barrier();
  __builtin_amdgcn_sched_barrier(0);
}
// LDS-only barrier: drains lgkmcnt but NOT vmcnt.
static __device__ inline void lds_barrier() {
  __builtin_amdgcn_sched_barrier(0);
  asm volatile("s_waitcnt lgkmcnt(0)" ::: "memory");
  __builtin_amdgcn_s_barrier();
  __builtin_amdgcn_sched_barrier(0);
}

// DPP row_ror:k (VALU-latency cross-lane)
#define DPP_ROR(x, k) __builtin_bit_cast(float, __builtin_amdgcn_update_dpp( \
    __builtin_bit_cast(int, x), __builtin_bit_cast(int, x), 0x120 | (k), 0xF, 0xF, false))

static __device__ inline float rowmax16(float v) {
  v = fmaxf(v, DPP_ROR(v, 1));
  v = fmaxf(v, DPP_ROR(v, 2));
  v = fmaxf(v, DPP_ROR(v, 4));
  v = fmaxf(v, DPP_ROR(v, 8));
  return v;
}
static __device__ inline float rowsum16(float v) {
  v += DPP_ROR(v, 1);
  v += DPP_ROR(v, 2);
  v += DPP_ROR(v, 4);
  v += DPP_ROR(v, 8);
  return v;
}

// ---------- fp32 -> bf16 convert, two tensors in ONE dispatch (R20-proven) ----------
__global__ __launch_bounds__(256) void f2b2_kernel(const float* __restrict__ in1,
                                                   unsigned short* __restrict__ out1,
                                                   int n1,
                                                   const float* __restrict__ in2,
                                                   unsigned short* __restrict__ out2,
                                                   int n2) {
  int c = blockIdx.x * 256 + threadIdx.x;
  const int c1 = n1 >> 2;
  const float* in;
  unsigned short* out;
  if (c < c1) {
    in = in1; out = out1;
  } else {
    c -= c1;
    if (c >= (n2 >> 2)) return;
    in = in2; out = out2;
  }
  const int i = c * 4;
  float4 v = *reinterpret_cast<const float4*>(in + i);
  ushort4 o;
  o.x = f2bf(v.x); o.y = f2bf(v.y); o.z = f2bf(v.z); o.w = f2bf(v.w);
  *reinterpret_cast<ushort4*>(out + i) = o;
}

// ================= GEMM1: 256x256 tile, BK=32, depth-3 counted-vmcnt pipeline =================
// R19-proven: swizzle key (row>>1)&3 (2-way bank aliasing = free, m136).
__global__ __launch_bounds__(512, 2) void gemm256(const unsigned short* __restrict__ A,
                                                  const unsigned short* __restrict__ B,
                                                  unsigned short* __restrict__ C,
                                                  int M, int N, int K) {
  __shared__ unsigned short lds[4][2][256 * 32];   // [buf][A/B][row*32 + col]

  const int tid = threadIdx.x;
  const int w = tid >> 6, l = tid & 63;
  const int l16 = l & 15, lg = l >> 4;
  const int wr = w >> 2, wc = w & 3;
  const long mb = (long)blockIdx.y * 256, nb = (long)blockIdx.x * 256;

  const int lr = l >> 2;
  const int sw = (((l & 3) ^ ((lr >> 1) & 3)) * 8);   // pre-swizzled col (elements)
  const unsigned short* Ag = A + (mb + w * 32 + lr) * (long)K + sw;
  const unsigned short* Bg = B + (nb + w * 32 + lr) * (long)K + sw;

  const int rdcol = ((lg ^ ((l16 >> 1) & 3)) * 16);   // matching read swizzle

  const fx4 fz = {0.f, 0.f, 0.f, 0.f};
  fx4 acc[8][4];
#pragma unroll
  for (int i = 0; i < 8; ++i)
#pragma unroll
    for (int j = 0; j < 4; ++j) acc[i][j] = fz;

  const int nt = K >> 5;   // K/32 tiles

  auto stage = [&](int tp) {
    const int db = tp & 3;
    const unsigned short* as = Ag + tp * 32;
    const unsigned short* bs = Bg + tp * 32;
    char* al = (char*)&lds[db][0][0] + w * 32 * 64;
    char* bl = (char*)&lds[db][1][0] + w * 32 * 64;
    gload16(as, al);
    gload16(as + 16 * (long)K, al + 1024);
    gload16(bs, bl);
    gload16(bs + 16 * (long)K, bl + 1024);
  };

  auto compute = [&](int bt) {
    const char* Ab = (const char*)&lds[bt][0][0] + (wr * 128 + l16) * 64 + rdcol;
    const char* Bb = (const char*)&lds[bt][1][0] + (wc * 64 + l16) * 64 + rdcol;
    bx8 bf[4];
#pragma unroll
    for (int nf = 0; nf < 4; ++nf)
      bf[nf] = *reinterpret_cast<const bx8*>(Bb + nf * 1024);
    __builtin_amdgcn_s_setprio(1);
#pragma unroll
    for (int mf = 0; mf < 8; ++mf) {
      bx8 av = *reinterpret_cast<const bx8*>(Ab + mf * 1024);
#pragma unroll
      for (int nf = 0; nf < 4; ++nf)
        acc[mf][nf] = mfma16(av, bf[nf], acc[mf][nf]);
    }
    __builtin_amdgcn_s_setprio(0);
  };

  stage(0); stage(1); stage(2);
  VMCNT(8);
  wave_barrier();

  int t = 0;
  for (; t < nt - 3; ++t) {
    stage(t + 3);
    compute(t & 3);
    VMCNT(8);
    wave_barrier();
  }
  compute(t & 3); VMCNT(4); wave_barrier(); ++t;
  compute(t & 3); VMCNT(0); wave_barrier(); ++t;
  compute(t & 3);

#pragma unroll
  for (int mf = 0; mf < 8; ++mf)
#pragma unroll
    for (int nf = 0; nf < 4; ++nf)
#pragma unroll
      for (int r = 0; r < 4; ++r) {
        const long row = mb + wr * 128 + mf * 16 + lg * 4 + r;
        const long col = nb + wc * 64 + nf * 16 + l16;
        C[row * N + col] = f2bf(acc[mf][nf][r]);
      }
}

// ---------- staging-reg type per operand dtype (R8-proven fold GEMM) ----------
template <typename T> struct RegOf { using type = us8; };
template <> struct RegOf<float>  { using type = fl8; };

template <typename T>
static __device__ inline typename RegOf<T>::type load8(const T* p) {
  return *reinterpret_cast<const typename RegOf<T>::type*>(p);
}
static __device__ inline us8 toBf(us8 v) { return v; }
static __device__ inline us8 toBf(fl8 f) {
  us8 o;
#pragma unroll
  for (int j = 0; j < 8; ++j) {
    __bf16 b = (__bf16)f[j];
    o[j] = __builtin_bit_cast(unsigned short, b);
  }
  return o;
}

// ---------- GEMM2: R8/R15-proven 128x128 reg-staged fold kernel + vmcnt-free barriers ----------
template <typename TA, typename TB, bool F32OUT>
__global__ __launch_bounds__(256) void gemm_bt(const TA* __restrict__ A,
                                               const TB* __restrict__ B,
                                               void* __restrict__ Cp,
                                               int M, int N, int K) {
  __shared__ alignas(16) unsigned short As[128 * 64];
  __shared__ alignas(16) unsigned short Bs[128 * 64];
  const int tid = threadIdx.x;
  const int w = tid >> 6, l = tid & 63;
  const int l16 = l & 15, lg = l >> 4;
  const int wr = w >> 1, wc = w & 1;
  const long mb = (long)blockIdx.y * 128, nb = (long)blockIdx.x * 128;

  const fx4 fz = {0.f, 0.f, 0.f, 0.f};
  fx4 acc[4][4];
#pragma unroll
  for (int i = 0; i < 4; ++i)
#pragma unroll
    for (int j = 0; j < 4; ++j) acc[i][j] = fz;

  const int sr  = tid >> 3;
  const int sc8 = (tid & 7) * 8;
  const int wbc = sc8 * 2;

  typename RegOf<TA>::type rA[4];
  typename RegOf<TB>::type rB[4];

#pragma unroll
  for (int p = 0; p < 4; ++p) {
    const int row = p * 32 + sr;
    rA[p] = load8(A + (mb + row) * (long)K + sc8);
    rB[p] = load8(B + (nb + row) * (long)K + sc8);
  }

  for (int k0 = 0; k0 < K; k0 += 64) {
    lds_barrier();   // prior iter's LDS reads done (no vmcnt drain)
#pragma unroll
    for (int p = 0; p < 4; ++p) {
      const int row = p * 32 + sr;
      const int eo = row * 64 + ((wbc ^ ((row & 7) << 4)) >> 1);
      *reinterpret_cast<us8*>(&As[eo]) = toBf(rA[p]);
      *reinterpret_cast<us8*>(&Bs[eo]) = toBf(rB[p]);
    }
    if (k0 + 64 < K) {
#pragma unroll
      for (int p = 0; p < 4; ++p) {
        const int row = p * 32 + sr;
        rA[p] = load8(A + (mb + row) * (long)K + k0 + 64 + sc8);
        rB[p] = load8(B + (nb + row) * (long)K + k0 + 64 + sc8);
      }
    }
    lds_barrier();   // tiles resident; prefetch loads stay in flight
#pragma unroll
    for (int kk = 0; kk < 2; ++kk) {
      bx8 a[4], b[4];
#pragma unroll
      for (int mf = 0; mf < 4; ++mf) {
        const int ra = wr * 64 + mf * 16 + l16;
        const int bc = kk * 64 + lg * 16;
        a[mf] = *reinterpret_cast<const bx8*>(&As[ra * 64 + ((bc ^ ((ra & 7) << 4)) >> 1)]);
      }
#pragma unroll
      for (int nf = 0; nf < 4; ++nf) {
        const int rb_ = wc * 64 + nf * 16 + l16;
        const int bc = kk * 64 + lg * 16;
        b[nf] = *reinterpret_cast<const bx8*>(&Bs[rb_ * 64 + ((bc ^ ((rb_ & 7) << 4)) >> 1)]);
      }
#pragma unroll
      for (int mf = 0; mf < 4; ++mf)
#pragma unroll
        for (int nf = 0; nf < 4; ++nf)
          acc[mf][nf] = mfma16(a[mf], b[nf], acc[mf][nf]);
    }
  }

#pragma unroll
  for (int mf = 0; mf < 4; ++mf)
#pragma unroll
    for (int nf = 0; nf < 4; ++nf)
#pragma unroll
      for (int r = 0; r < 4; ++r) {
        const long row = mb + wr * 64 + mf * 16 + lg * 4 + r;
        const long col = nb + wc * 64 + nf * 16 + l16;
        if (F32OUT)
          ((float*)Cp)[row * N + col] = acc[mf][nf][r];
        else
          ((unsigned short*)Cp)[row * N + col] = f2bf(acc[mf][nf][r]);
      }
}

// ---------- flash attention (causal) — R18-proven body + T5 setprio around MFMA clusters ----------
__global__ __launch_bounds__(256) void fa_kernel(const unsigned short* __restrict__ qkv,
                                                 unsigned short* __restrict__ Obuf,
                                                 float* __restrict__ ML) {
  __shared__ alignas(16) char smem[73728];

  const int id = blockIdx.x;
  const int h = id & 15, i = id >> 4;
  int qt, ck;
  if (i < 32)      { qt = 31 - (i >> 2); ck = i & 3; }
  else if (i < 56) { const int j = i - 32; qt = 23 - j / 3; ck = j % 3; }
  else if (i < 72) { const int j = i - 56; qt = 15 - (j >> 1); ck = j & 1; }
  else             { qt = 7 - (i - 72); ck = 0; }
  const int t0 = ck * 8;
  const int t1 = min(t0 + 8, qt + 1);
  const int qb = qt * 64;

  const int tid = threadIdx.x;
  const int w = tid >> 6, l = tid & 63;
  const int l16 = l & 15, lg = l >> 4;
  const fx4 fz = {0.f, 0.f, 0.f, 0.f};

  const int kr = tid >> 4, ksl = tid & 15;
  const int kg = tid & 15, db = tid >> 4;
  const int kc8 = ksl * 8;

  bx8 qf[4];
  {
    const long qrow = qb + w * 16 + l16;
    const unsigned short* qp = qkv + qrow * 6144L + h * 128 + lg * 8;
#pragma unroll
    for (int kc = 0; kc < 4; ++kc)
      qf[kc] = *reinterpret_cast<const bx8*>(qp + kc * 32);
  }

  fx4 o_acc[8];
#pragma unroll
  for (int i2 = 0; i2 < 8; ++i2) o_acc[i2] = fz;
  float m_r[4] = {-3e38f, -3e38f, -3e38f, -3e38f};
  float l_r[4] = {0.f, 0.f, 0.f, 0.f};

  us8 rK[4], rV[4];
  {
    const long kvb = (long)t0 * 64;
#pragma unroll
    for (int p = 0; p < 4; ++p)
      rK[p] = *reinterpret_cast<const us8*>(qkv + (kvb + p * 16 + kr) * 6144L + 2048 + h * 128 + kc8);
#pragma unroll
    for (int p = 0; p < 4; ++p)
      rV[p] = *reinterpret_cast<const us8*>(qkv + (kvb + kg * 4 + p) * 6144L + 4096 + h * 128 + db * 8);
  }

  const float sc2 = 0.1275173831f;  // (1/sqrt(128)) * log2(e)
  char* const psb = smem + 65536 + w * 2048;

  for (int t = t0; t < t1; ++t) {
    char* const buf = smem + (((t - t0) & 1) << 15);   // 0 or 32768

#pragma unroll
    for (int p = 0; p < 4; ++p)
      *reinterpret_cast<us8*>(buf + (p * 16 + kr) * 256 + ((ksl ^ kr) << 4)) = rK[p];
#pragma unroll
    for (int j = 0; j < 8; ++j) {
      us4 vw = {rV[0][j], rV[1][j], rV[2][j], rV[3][j]};
      *reinterpret_cast<us4*>(buf + 16384 + (db * 8 + j) * 128 +
                              (((kg >> 1) ^ j) << 4) + ((kg & 1) << 3)) = vw;
    }

    if (t + 1 < t1) {
      const long kvb = (long)(t + 1) * 64;
#pragma unroll
      for (int p = 0; p < 4; ++p)
        rK[p] = *reinterpret_cast<const us8*>(qkv + (kvb + p * 16 + kr) * 6144L + 2048 + h * 128 + kc8);
#pragma unroll
      for (int p = 0; p < 4; ++p)
        rV[p] = *reinterpret_cast<const us8*>(qkv + (kvb + kg * 4 + p) * 6144L + 4096 + h * 128 + db * 8);
    }

    lds_barrier();   // single barrier per step

    // --- S = Q * K^T (T5: boost MFMA-issuing wave over other blocks' VALU waves) ---
    fx4 s[4];
#pragma unroll
    for (int nf = 0; nf < 4; ++nf) s[nf] = fz;
    __builtin_amdgcn_s_setprio(1);
#pragma unroll
    for (int kc = 0; kc < 4; ++kc) {
#pragma unroll
      for (int nf = 0; nf < 4; ++nf) {
        const int rl = nf * 16 + l16;
        bx8 kb = *reinterpret_cast<const bx8*>(buf + rl * 256 + (((kc * 4 + lg) ^ l16) << 4));
        s[nf] = mfma16(qf[kc], kb, s[nf]);
      }
    }
    __builtin_amdgcn_s_setprio(0);

    if (t == qt) {
#pragma unroll
      for (int nf = 0; nf < 4; ++nf) {
        const int kv_abs = t * 64 + nf * 16 + l16;
#pragma unroll
        for (int r = 0; r < 4; ++r) {
          const int q_abs = qb + w * 16 + lg * 4 + r;
          if (kv_abs > q_abs) s[nf][r] = -3e38f;
        }
      }
    }

    float rm_[4];
    bool st = true;
#pragma unroll
    for (int r = 0; r < 4; ++r) {
      float rm = fmaxf(fmaxf(s[0][r], s[1][r]), fmaxf(s[2][r], s[3][r]));
      rm_[r] = rowmax16(rm);
      st = st && (rm_[r] - m_r[r] <= 62.7f);
    }
    float pv[4][4];
    if (__all(st ? 1 : 0)) {
#pragma unroll
      for (int r = 0; r < 4; ++r) {
        float rs = 0.f;
#pragma unroll
        for (int nf = 0; nf < 4; ++nf) {
          const float p = exp2f((s[nf][r] - m_r[r]) * sc2);
          pv[nf][r] = p;
          rs += p;
        }
        l_r[r] += rowsum16(rs);
      }
    } else {
#pragma unroll
      for (int r = 0; r < 4; ++r) {
        const float mn = fmaxf(m_r[r], rm_[r]);
        const float fac = exp2f((m_r[r] - mn) * sc2);
        m_r[r] = mn;
        float rs = 0.f;
#pragma unroll
        for (int nf = 0; nf < 4; ++nf) {
          const float p = exp2f((s[nf][r] - mn) * sc2);
          pv[nf][r] = p;
          rs += p;
        }
        l_r[r] = l_r[r] * fac + rowsum16(rs);
#pragma unroll
        for (int nf = 0; nf < 8; ++nf) o_acc[nf][r] *= fac;
      }
    }

#pragma unroll
    for (int nf = 0; nf < 4; ++nf)
#pragma unroll
      for (int r = 0; r < 4; ++r) {
        const int ro = lg * 4 + r;
        *reinterpret_cast<unsigned short*>(
            psb + ro * 128 + (((nf * 2 + (l16 >> 3)) ^ (ro & 7)) << 4) + ((l16 & 7) << 1)) =
            __builtin_bit_cast(unsigned short, (__bf16)pv[nf][r]);
      }

    bx8 pa[2];
#pragma unroll
    for (int kc = 0; kc < 2; ++kc)
      pa[kc] = *reinterpret_cast<const bx8*>(psb + l16 * 128 + (((kc * 4 + lg) ^ (l16 & 7)) << 4));

    // --- O += P * V (T5) ---
    __builtin_amdgcn_s_setprio(1);
#pragma unroll
    for (int nf = 0; nf < 8; ++nf) {
#pragma unroll
      for (int kc = 0; kc < 2; ++kc) {
        bx8 vb = *reinterpret_cast<const bx8*>(buf + 16384 + (nf * 16 + l16) * 128 +
                                               (((kc * 4 + lg) ^ (l16 & 7)) << 4));
        o_acc[nf] = mfma16(pa[kc], vb, o_acc[nf]);
      }
    }
    __builtin_amdgcn_s_setprio(0);
  }

  unsigned short* ob = Obuf + (long)id * 8192;
#pragma unroll
  for (int nf = 0; nf < 8; ++nf)
#pragma unroll
    for (int r = 0; r < 4; ++r) {
      const int row = w * 16 + lg * 4 + r;
      ob[row * 128 + nf * 16 + l16] = f2bf(o_acc[nf][r]);
    }
  if (l16 == 0) {
#pragma unroll
    for (int r = 0; r < 4; ++r) {
      const int row = w * 16 + lg * 4 + r;
      ML[((long)id * 64 + row) * 2 + 0] = m_r[r];
      ML[((long)id * 64 + row) * 2 + 1] = l_r[r];
    }
  }
}

// ---------- combine <=4 chunk partials into attnb (R11-proven) ----------
__global__ __launch_bounds__(256) void fa_combine(const unsigned short* __restrict__ Obuf,
                                                  const float* __restrict__ ML,
                                                  unsigned short* __restrict__ out) {
  const int p = blockIdx.x;
  const int qt = p >> 4, h = p & 15;
  const int nc = (qt + 8) >> 3;
  const int tid = threadIdx.x;
  const int row = tid >> 2;
  const int c0 = (tid & 3) * 32;
  const float sc2 = 0.1275173831f;

  int ids[4];
#pragma unroll
  for (int k = 0; k < 4; ++k) {
    int ib;
    if (qt >= 24)      ib = (31 - qt) * 4 + k;
    else if (qt >= 16) ib = 32 + (23 - qt) * 3 + k;
    else if (qt >= 8)  ib = 56 + (15 - qt) * 2 + k;
    else               ib = 72 + (7 - qt);
    ids[k] = ib * 16 + h;
  }

  float mk[4], lk[4];
  float m = -3e38f;
#pragma unroll
  for (int k = 0; k < 4; ++k)
    if (k < nc) {
      mk[k] = ML[((long)ids[k] * 64 + row) * 2 + 0];
      lk[k] = ML[((long)ids[k] * 64 + row) * 2 + 1];
      m = fmaxf(m, mk[k]);
    }
  float fk[4], denom = 0.f;
#pragma unroll
  for (int k = 0; k < 4; ++k)
    if (k < nc) {
      fk[k] = exp2f((mk[k] - m) * sc2);
      denom += lk[k] * fk[k];
    }
  const float inv = 1.0f / denom;

  float acc[32];
#pragma unroll
  for (int j = 0; j < 32; ++j) acc[j] = 0.f;
#pragma unroll
  for (int k = 0; k < 4; ++k)
    if (k < nc) {
      const unsigned short* ob = Obuf + (long)ids[k] * 8192 + row * 128 + c0;
      const float f = fk[k];
#pragma unroll
      for (int jj = 0; jj < 4; ++jj) {
        us8 a = *reinterpret_cast<const us8*>(ob + jj * 8);
#pragma unroll
        for (int j2 = 0; j2 < 8; ++j2) acc[jj * 8 + j2] += bf2f(a[j2]) * f;
      }
    }

  unsigned short* dst = out + (long)(qt * 64 + row) * 2048 + h * 128 + c0;
#pragma unroll
  for (int jj = 0; jj < 4; ++jj) {
    ushort4 o0, o1;
    o0.x = f2bf(acc[jj * 8 + 0] * inv);
    o0.y = f2bf(acc[jj * 8 + 1] * inv);
    o0.z = f2bf(acc[jj * 8 + 2] * inv);
    o0.w = f2bf(acc[jj * 8 + 3] * inv);
    o1.x = f2bf(acc[jj * 8 + 4] * inv);
    o1.y = f2bf(acc[jj * 8 + 5] * inv);
    o1.z = f2bf(acc[jj * 8 + 6] * inv);
    o1.w = f2bf(acc[jj * 8 + 7] * inv);
    *reinterpret_cast<ushort4*>(dst + jj * 8) = o0;
    *reinterpret_cast<ushort4*>(dst + jj * 8 + 4) = o1;
  }
}

// ---------- launch ----------
// Interface (confirmed R4): inputs fp32, output fp32.
// Workspace plan (peak 56 MiB):
//   wab   [0, 24 MiB)     bf16 W_attn (dead after GEMM1)
//   qkvb  [24, 48 MiB)    bf16 qkv
//   xb    [48, 56 MiB)    bf16 x (dead after GEMM1)
//   -- after GEMM1, overlaying dead regions:
//   Obuf  [0, 20 MiB)     1280 x 64x128 bf16 partial O numerators
//   ML    [20, 20.625)    1280 x 64 x (m,l) fp32
//   attnb [48, 56 MiB)    bf16 attn out (overlays dead xb)
extern "C" void kernel_launch(void* const* d_in, const int* in_sizes, int n_in,
                              void* d_out, int out_size, void* d_ws, size_t ws_size,
                              hipStream_t stream) {
  const float* x  = (const float*)d_in[0];   // (2048, 2048) fp32
  const float* Wa = (const float*)d_in[1];   // (6144, 2048) fp32
  const float* Wp = (const float*)d_in[2];   // (2048, 2048) fp32
  float* out = (float*)d_out;                // (2048, 2048) fp32
  char* ws = (char*)d_ws;

  unsigned short* wab   = (unsigned short*)(ws);                 // 24 MiB
  unsigned short* qkvb  = (unsigned short*)(ws + (24ull << 20)); // 24 MiB
  unsigned short* xb    = (unsigned short*)(ws + (48ull << 20)); //  8 MiB
  unsigned short* Obuf  = (unsigned short*)(ws);                 // 20 MiB (after GEMM1)
  float*          ML    = (float*)(ws + (20ull << 20));          // 640 KiB (after GEMM1)
  unsigned short* attnb = (unsigned short*)(ws + (48ull << 20)); //  8 MiB (after GEMM1)

  // x and W_attn fp32->bf16 in ONE dispatch (4M + 12M elems = 16384 blocks)
  f2b2_kernel<<<16384, 256, 0, stream>>>(x, xb, 2048 * 2048, Wa, wab, 6144 * 2048);

  // qkv = x @ W_attn^T : M=2048, N=6144, K=2048 — deep-pipelined 256^2 kernel
  gemm256<<<dim3(24, 8), 512, 0, stream>>>(xb, wab, qkvb, 2048, 6144, 2048);

  // causal flash attention: 1280 uniform 8-tile chunk items (heavy first)
  fa_kernel<<<1280, 256, 0, stream>>>(qkvb, Obuf, ML);

  // merge 1..4 chunk partials per (qt, h)
  fa_combine<<<512, 256, 0, stream>>>(Obuf, ML, attnb);

  // out = attn @ W_proj^T : M=2048, N=2048, K=2048 (A bf16, B fp32 fold, fp32 out)
  gemm_bt<unsigned short, float, true><<<dim3(16, 16), 256, 0, stream>>>(attnb, Wp, (void*)out, 2048, 2048, 2048);
}